// Round 1
// baseline (988.345 us; speedup 1.0000x reference)
//
#include <hip/hip_runtime.h>
#include <math.h>

// Problem constants
#define B_ 2
#define S_ 2048
#define C_ 1024
#define H_ 16
#define D_ 64

__device__ __forceinline__ float tanh_fast(float z) {
    z = fminf(fmaxf(z, -15.f), 15.f);
    float e = __expf(2.f * z);
    return __fdividef(e - 1.f, e + 1.f);
}

__device__ __forceinline__ float mish_f(float x) {
    float sp = (x > 15.f) ? x : log1pf(__expf(x));
    return x * tanh_fast(sp);
}

// -------------------------------------------------------------------------
// Generic fp32 GEMM: Cout = op(A @ W + bias), tiles 128x128xBK16, 8x8/thread
// grid: (N/128, M/128, batch); strides sA/sW/sC applied per blockIdx.z
// -------------------------------------------------------------------------
__global__ __launch_bounds__(256) void gemm_bias(
    const float* __restrict__ A, const float* __restrict__ W,
    const float* __restrict__ bias, float* __restrict__ Cout,
    int M, int N, int K, long sA, long sW, long sC, int do_mish)
{
    A    += (size_t)blockIdx.z * sA;
    W    += (size_t)blockIdx.z * sW;
    Cout += (size_t)blockIdx.z * sC;

    __shared__ float As[16][128];   // [k][m]
    __shared__ float Bs[16][128];   // [k][n]

    const int t  = threadIdx.x;
    const int tx = t & 15, ty = t >> 4;
    const int row0 = blockIdx.y * 128, col0 = blockIdx.x * 128;

    const int ar  = t >> 2;         // 0..63  (A row within tile)
    const int ak  = (t & 3) << 2;   // 0,4,8,12 (k within tile)
    const int wr  = t >> 5;         // 0..7   (W row within tile)
    const int wcc = (t & 31) << 2;  // 0..124 (n within tile)

    float acc[8][8] = {};

    for (int k0 = 0; k0 < K; k0 += 16) {
        float4 a0 = *(const float4*)&A[(size_t)(row0 + ar)      * K + k0 + ak];
        float4 a1 = *(const float4*)&A[(size_t)(row0 + ar + 64) * K + k0 + ak];
        float4 w0 = *(const float4*)&W[(size_t)(k0 + wr)     * N + col0 + wcc];
        float4 w1 = *(const float4*)&W[(size_t)(k0 + wr + 8) * N + col0 + wcc];
        __syncthreads();
        As[ak + 0][ar] = a0.x; As[ak + 1][ar] = a0.y;
        As[ak + 2][ar] = a0.z; As[ak + 3][ar] = a0.w;
        As[ak + 0][ar + 64] = a1.x; As[ak + 1][ar + 64] = a1.y;
        As[ak + 2][ar + 64] = a1.z; As[ak + 3][ar + 64] = a1.w;
        *(float4*)&Bs[wr][wcc]     = w0;
        *(float4*)&Bs[wr + 8][wcc] = w1;
        __syncthreads();
        #pragma unroll
        for (int kk = 0; kk < 16; ++kk) {
            float av[8], bv[8];
            *(float4*)&av[0] = *(const float4*)&As[kk][ty * 8];
            *(float4*)&av[4] = *(const float4*)&As[kk][ty * 8 + 4];
            *(float4*)&bv[0] = *(const float4*)&Bs[kk][tx * 8];
            *(float4*)&bv[4] = *(const float4*)&Bs[kk][tx * 8 + 4];
            #pragma unroll
            for (int i = 0; i < 8; ++i)
                #pragma unroll
                for (int j = 0; j < 8; ++j)
                    acc[i][j] = fmaf(av[i], bv[j], acc[i][j]);
        }
    }

    #pragma unroll
    for (int i = 0; i < 8; ++i) {
        int r = row0 + ty * 8 + i;
        #pragma unroll
        for (int j4 = 0; j4 < 8; j4 += 4) {
            int c = col0 + tx * 8 + j4;
            float4 bb = *(const float4*)&bias[c];
            float4 o;
            o.x = acc[i][j4 + 0] + bb.x;
            o.y = acc[i][j4 + 1] + bb.y;
            o.z = acc[i][j4 + 2] + bb.z;
            o.w = acc[i][j4 + 3] + bb.w;
            if (do_mish) {
                o.x = mish_f(o.x); o.y = mish_f(o.y);
                o.z = mish_f(o.z); o.w = mish_f(o.w);
            }
            *(float4*)&Cout[(size_t)r * N + c] = o;
        }
    }
}

// -------------------------------------------------------------------------
// cv[bh,k,d] = sum_s tanh(t_mat[b,k,s]*wc[h]+bc[h]) * V[b,s,h*64+d]
// per-block: 64 k-rows x 64 d, K-loop over s in chunks of 32 (fused tanh)
// grid: (S/64, 1, BH)
// -------------------------------------------------------------------------
__global__ __launch_bounds__(256) void cv_kernel(
    const float* __restrict__ t_mat, const float* __restrict__ V,
    const float* __restrict__ wc, const float* __restrict__ bc,
    float* __restrict__ CV)
{
    const int bh = blockIdx.z, b = bh >> 4, h = bh & 15;
    const int k0 = blockIdx.x * 64;
    const int t = threadIdx.x;
    const int tx = t & 15, ty = t >> 4;
    const float wch = wc[h], bch = bc[h];

    __shared__ float As[32][64];  // [s][k]  (tanh-activated c, transposed)
    __shared__ float Bs[32][64];  // [s][d]

    const float* tb = t_mat + (size_t)b * S_ * S_;
    const float* Vb = V + (size_t)b * S_ * C_ + h * 64;

    const int ar  = t >> 2;         // 0..63 k-row
    const int asc = (t & 3) << 3;   // 0,8,16,24 s-col
    const int vr  = t >> 3;         // 0..31 s-row
    const int vdc = (t & 7) << 3;   // 0..56 d-col

    float acc[4][4] = {};

    for (int s0 = 0; s0 < S_; s0 += 32) {
        const float* trow = &tb[(size_t)(k0 + ar) * S_ + s0 + asc];
        float4 t0 = *(const float4*)&trow[0];
        float4 t1 = *(const float4*)&trow[4];
        const float* vrow = &Vb[(size_t)(s0 + vr) * C_ + vdc];
        float4 v0 = *(const float4*)&vrow[0];
        float4 v1 = *(const float4*)&vrow[4];
        __syncthreads();
        As[asc + 0][ar] = tanh_fast(fmaf(t0.x, wch, bch));
        As[asc + 1][ar] = tanh_fast(fmaf(t0.y, wch, bch));
        As[asc + 2][ar] = tanh_fast(fmaf(t0.z, wch, bch));
        As[asc + 3][ar] = tanh_fast(fmaf(t0.w, wch, bch));
        As[asc + 4][ar] = tanh_fast(fmaf(t1.x, wch, bch));
        As[asc + 5][ar] = tanh_fast(fmaf(t1.y, wch, bch));
        As[asc + 6][ar] = tanh_fast(fmaf(t1.z, wch, bch));
        As[asc + 7][ar] = tanh_fast(fmaf(t1.w, wch, bch));
        *(float4*)&Bs[vr][vdc]     = v0;
        *(float4*)&Bs[vr][vdc + 4] = v1;
        __syncthreads();
        #pragma unroll
        for (int kk = 0; kk < 32; ++kk) {
            float av[4], bv[4];
            *(float4*)&av[0] = *(const float4*)&As[kk][ty * 4];
            *(float4*)&bv[0] = *(const float4*)&Bs[kk][tx * 4];
            #pragma unroll
            for (int i = 0; i < 4; ++i)
                #pragma unroll
                for (int j = 0; j < 4; ++j)
                    acc[i][j] = fmaf(av[i], bv[j], acc[i][j]);
        }
    }

    float* outp = CV + ((size_t)bh * S_ + k0) * D_;
    #pragma unroll
    for (int i = 0; i < 4; ++i)
        #pragma unroll
        for (int j = 0; j < 4; ++j)
            outp[(size_t)(ty * 4 + i) * D_ + tx * 4 + j] = acc[i][j];
}

// -------------------------------------------------------------------------
// M[bh,d',d] = sum_q Q[b,q,h*64+d'] * cv[bh,q,d]   (64x64 per head)
// grid: (8 k-splits of 256 q, BH); atomicAdd partials (Mm pre-zeroed)
// -------------------------------------------------------------------------
__global__ __launch_bounds__(256) void qtcv_kernel(
    const float* __restrict__ Q, const float* __restrict__ CV,
    float* __restrict__ Mm)
{
    const int bh = blockIdx.y, b = bh >> 4, h = bh & 15;
    const int q0 = blockIdx.x * 256;
    const int t = threadIdx.x;
    const int tx = t & 15, ty = t >> 4;

    __shared__ float Qs[32][64];  // [q][d']
    __shared__ float Cs[32][64];  // [q][d]

    const float* Qb = Q + (size_t)b * S_ * C_ + h * 64;
    const float* Cb = CV + (size_t)bh * S_ * D_;

    const int r  = t >> 3;        // 0..31
    const int cc = (t & 7) << 3;  // 0..56

    float acc[4][4] = {};

    for (int qc = 0; qc < 256; qc += 32) {
        int q = q0 + qc + r;
        float4 a0 = *(const float4*)&Qb[(size_t)q * C_ + cc];
        float4 a1 = *(const float4*)&Qb[(size_t)q * C_ + cc + 4];
        float4 c0 = *(const float4*)&Cb[(size_t)q * D_ + cc];
        float4 c1 = *(const float4*)&Cb[(size_t)q * D_ + cc + 4];
        __syncthreads();
        *(float4*)&Qs[r][cc]     = a0;
        *(float4*)&Qs[r][cc + 4] = a1;
        *(float4*)&Cs[r][cc]     = c0;
        *(float4*)&Cs[r][cc + 4] = c1;
        __syncthreads();
        #pragma unroll
        for (int kk = 0; kk < 32; ++kk) {
            float av[4], bv[4];
            *(float4*)&av[0] = *(const float4*)&Qs[kk][ty * 4];
            *(float4*)&bv[0] = *(const float4*)&Cs[kk][tx * 4];
            #pragma unroll
            for (int i = 0; i < 4; ++i)
                #pragma unroll
                for (int j = 0; j < 4; ++j)
                    acc[i][j] = fmaf(av[i], bv[j], acc[i][j]);
        }
    }

    float* mp = Mm + (size_t)bh * 64 * 64;
    #pragma unroll
    for (int i = 0; i < 4; ++i)
        #pragma unroll
        for (int j = 0; j < 4; ++j)
            atomicAdd(&mp[(size_t)(ty * 4 + i) * 64 + tx * 4 + j], acc[i][j]);
}

// -------------------------------------------------------------------------
// Weff[b, h*64+d', co] = (1/8) * sum_d M[bh,d',d] * wf[h*64+d, co]
// grid: (C/64, H, B); one 64x64 tile per block, K=64
// -------------------------------------------------------------------------
__global__ __launch_bounds__(256) void weff_kernel(
    const float* __restrict__ Mm, const float* __restrict__ wf,
    float* __restrict__ Weff)
{
    const int b = blockIdx.z, h = blockIdx.y;
    const int co0 = blockIdx.x * 64;
    const int t = threadIdx.x;
    const int tx = t & 15, ty = t >> 4;

    __shared__ float Ms[64][64];  // [d][d']  (M transposed)
    __shared__ float Ws[64][64];  // [d][co]

    const float* Mb = Mm + (size_t)(b * H_ + h) * 64 * 64;

    const int r  = t >> 2;        // 0..63
    const int c4 = (t & 3) << 2;  // 0,4,8,12

    #pragma unroll
    for (int rep = 0; rep < 4; ++rep) {
        int col = c4 + rep * 16;
        float4 m4 = *(const float4*)&Mb[(size_t)r * 64 + col];
        Ms[col + 0][r] = m4.x; Ms[col + 1][r] = m4.y;
        Ms[col + 2][r] = m4.z; Ms[col + 3][r] = m4.w;
        float4 w4 = *(const float4*)&wf[(size_t)(h * 64 + r) * C_ + co0 + col];
        *(float4*)&Ws[r][col] = w4;
    }
    __syncthreads();

    float acc[4][4] = {};
    #pragma unroll
    for (int kk = 0; kk < 64; ++kk) {
        float av[4], bv[4];
        *(float4*)&av[0] = *(const float4*)&Ms[kk][ty * 4];
        *(float4*)&bv[0] = *(const float4*)&Ws[kk][tx * 4];
        #pragma unroll
        for (int i = 0; i < 4; ++i)
            #pragma unroll
            for (int j = 0; j < 4; ++j)
                acc[i][j] = fmaf(av[i], bv[j], acc[i][j]);
    }

    float* wp = Weff + (size_t)b * C_ * C_;
    #pragma unroll
    for (int i = 0; i < 4; ++i)
        #pragma unroll
        for (int j = 0; j < 4; ++j)
            wp[(size_t)(h * 64 + ty * 4 + i) * C_ + co0 + tx * 4 + j] =
                acc[i][j] * 0.125f;  // fold 1/sqrt(D)=1/8
}

// -------------------------------------------------------------------------
extern "C" void kernel_launch(void* const* d_in, const int* in_sizes, int n_in,
                              void* d_out, int out_size, void* d_ws, size_t ws_size,
                              hipStream_t stream) {
    const float* x     = (const float*)d_in[0];
    const float* y     = (const float*)d_in[1];
    const float* t_mat = (const float*)d_in[2];
    const float* wq    = (const float*)d_in[3];
    const float* bq    = (const float*)d_in[4];
    const float* wk    = (const float*)d_in[5];
    const float* bk    = (const float*)d_in[6];
    const float* wv    = (const float*)d_in[7];
    const float* bv    = (const float*)d_in[8];
    const float* wc    = (const float*)d_in[9];
    const float* bc    = (const float*)d_in[10];
    const float* wf    = (const float*)d_in[11];
    const float* bf    = (const float*)d_in[12];
    float* out = (float*)d_out;

    // workspace layout (floats)
    float* ws   = (float*)d_ws;
    float* Qm   = ws;                    // (B,S,C)  4,194,304
    float* Km   = ws + 4194304;          // (B,S,C)
    float* Vm   = ws + 8388608;          // (B,S,C)
    float* CVm  = ws + 12582912;         // (BH,S,D) 4,194,304
    float* Mm   = ws + 16777216;         // (B,H,64,64) 131,072
    float* Weff = ws + 16908288;         // (B,C,C)  2,097,152

    hipMemsetAsync(Mm, 0, (size_t)B_ * H_ * 64 * 64 * sizeof(float), stream);

    dim3 blk(256);

    // QKV projections: 4096x1024x1024 each
    dim3 gproj(C_ / 128, (B_ * S_) / 128, 1);
    gemm_bias<<<gproj, blk, 0, stream>>>(y, wq, bq, Qm, B_ * S_, C_, C_, 0, 0, 0, 0);
    gemm_bias<<<gproj, blk, 0, stream>>>(x, wk, bk, Km, B_ * S_, C_, C_, 0, 0, 0, 0);
    gemm_bias<<<gproj, blk, 0, stream>>>(y, wv, bv, Vm, B_ * S_, C_, C_, 0, 0, 0, 0);

    // cv = tanh(t_mat*wc+bc) @ V per head
    cv_kernel<<<dim3(S_ / 64, 1, B_ * H_), blk, 0, stream>>>(t_mat, Vm, wc, bc, CVm);

    // M = Q^T @ cv per head (64x64), k-split with atomics
    qtcv_kernel<<<dim3(8, B_ * H_, 1), blk, 0, stream>>>(Qm, CVm, Mm);

    // Weff[b] = blockdiag(M) folded into wf, scaled 1/8
    weff_kernel<<<dim3(C_ / 64, H_, B_), blk, 0, stream>>>(Mm, wf, Weff);

    // out = mish(K_flat[b] @ Weff[b] + bf)
    gemm_bias<<<dim3(C_ / 128, S_ / 128, B_), blk, 0, stream>>>(
        Km, Weff, bf, out, S_, C_, C_,
        (long)S_ * C_, (long)C_ * C_, (long)S_ * C_, 1);
}

// Round 2
// 425.554 us; speedup vs baseline: 2.3225x; 2.3225x over previous
//
#include <hip/hip_runtime.h>
#include <math.h>

#define B_ 2
#define S_ 2048
#define C_ 1024
#define H_ 16
#define D_ 64

typedef __bf16 bf16_t;
typedef __attribute__((ext_vector_type(8))) __bf16 bf16x8;
typedef __attribute__((ext_vector_type(4))) __bf16 bf16x4;
typedef __attribute__((ext_vector_type(4))) float f32x4;

__device__ __forceinline__ void gload16(const void* g, void* l) {
    __builtin_amdgcn_global_load_lds(
        (const __attribute__((address_space(1))) unsigned int*)g,
        (__attribute__((address_space(3))) unsigned int*)l, 16, 0, 0);
}

__device__ __forceinline__ float tanh_fast(float z) {
    z = fminf(fmaxf(z, -12.f), 12.f);
    float e = __expf(2.f * z);
    return 1.f - __fdividef(2.f, e + 1.f);
}

__device__ __forceinline__ float mish_f(float x) {
    float sp = (x > 15.f) ? x : log1pf(__expf(x));
    return x * tanh_fast(sp);
}

// -------------------------------------------------------------------------
// Elementwise fp32 -> bf16 (two tensors via blockIdx.y)
// -------------------------------------------------------------------------
__global__ __launch_bounds__(256) void cvt2_bf16(
    const float* __restrict__ a, bf16_t* __restrict__ oa,
    const float* __restrict__ b, bf16_t* __restrict__ ob)
{
    size_t i = ((size_t)blockIdx.x * 256 + threadIdx.x) * 8;
    const float* in = blockIdx.y ? b : a;
    bf16_t* out = blockIdx.y ? ob : oa;
    float4 u = *(const float4*)&in[i];
    float4 v = *(const float4*)&in[i + 4];
    bf16x8 o;
    o[0] = (bf16_t)u.x; o[1] = (bf16_t)u.y; o[2] = (bf16_t)u.z; o[3] = (bf16_t)u.w;
    o[4] = (bf16_t)v.x; o[5] = (bf16_t)v.y; o[6] = (bf16_t)v.z; o[7] = (bf16_t)v.w;
    *(bf16x8*)&out[i] = o;
}

// -------------------------------------------------------------------------
// Transpose-convert weights [K,N] fp32 -> [N,K] bf16 (3 weights via z)
// -------------------------------------------------------------------------
__global__ __launch_bounds__(256) void wtrans_bf16(
    const float* __restrict__ w0, const float* __restrict__ w1,
    const float* __restrict__ w2,
    bf16_t* __restrict__ o0, bf16_t* __restrict__ o1, bf16_t* __restrict__ o2)
{
    const float* in = blockIdx.z == 0 ? w0 : (blockIdx.z == 1 ? w1 : w2);
    bf16_t* out = blockIdx.z == 0 ? o0 : (blockIdx.z == 1 ? o1 : o2);
    __shared__ float ts[64][65];
    const int t = threadIdx.x;
    const int k0 = blockIdx.y * 64, n0 = blockIdx.x * 64;
    const int r = t >> 2, c0 = (t & 3) * 16;
    #pragma unroll
    for (int j = 0; j < 16; j += 4) {
        float4 v = *(const float4*)&in[(size_t)(k0 + r) * C_ + n0 + c0 + j];
        ts[c0 + j + 0][r] = v.x; ts[c0 + j + 1][r] = v.y;
        ts[c0 + j + 2][r] = v.z; ts[c0 + j + 3][r] = v.w;
    }
    __syncthreads();
    #pragma unroll
    for (int g = 0; g < 2; ++g) {
        bf16x8 o;
        #pragma unroll
        for (int e = 0; e < 8; ++e) o[e] = (bf16_t)ts[r][c0 + g * 8 + e];
        *(bf16x8*)&out[(size_t)(n0 + r) * C_ + k0 + c0 + g * 8] = o;
    }
}

// -------------------------------------------------------------------------
// MFMA bf16 GEMM (m97 pattern): C = A[M,K] @ Bt[N,K]^T + bias
// 128x128 tile, BK=32, 4 waves 2x2, 16x16x32 MFMA, global_load_lds staging.
// mode: 0 = fp32 out, 1 = bf16 out, 2 = bf16 transposed per-batch (Vt),
//       3 = fp32 + mish
// -------------------------------------------------------------------------
__global__ __launch_bounds__(256) void mfma_gemm(
    const bf16_t* __restrict__ A, const bf16_t* __restrict__ Bt,
    const float* __restrict__ bias, void* __restrict__ Cout,
    int M, int N, int K, long sA, long sB, long sC, int mode)
{
    A  += (size_t)blockIdx.z * sA;
    Bt += (size_t)blockIdx.z * sB;

    __shared__ bf16_t As[128 * 32];
    __shared__ bf16_t Bs[128 * 32];

    const int t = threadIdx.x;
    const int w = t >> 6, lane = t & 63;
    const int wm = (w >> 1) * 64, wn = (w & 1) * 64;
    const int l15 = lane & 15, l4 = lane >> 4;
    const int row0 = blockIdx.y * 128, col0 = blockIdx.x * 128;

    // staging: linear L = r*256+t -> row = L>>2 (0..127), kel = (L&3)*8
    const int sr = t >> 2;
    const int sk = (t & 3) * 8;
    const bf16_t* gA = A + (size_t)(row0 + sr) * K + sk;
    const bf16_t* gB = Bt + (size_t)(col0 + sr) * K + sk;
    bf16_t* lA = As + (t & ~63) * 8;
    bf16_t* lB = Bs + (t & ~63) * 8;

    f32x4 acc[4][4] = {};

    for (int k0 = 0; k0 < K; k0 += 32) {
        __syncthreads();
        gload16(gA + k0, lA);
        gload16(gA + k0 + (size_t)64 * K, lA + 2048);
        gload16(gB + k0, lB);
        gload16(gB + k0 + (size_t)64 * K, lB + 2048);
        __syncthreads();
        bf16x8 a[4], b[4];
        #pragma unroll
        for (int i = 0; i < 4; ++i)
            a[i] = *(const bf16x8*)&As[(wm + i * 16 + l15) * 32 + l4 * 8];
        #pragma unroll
        for (int j = 0; j < 4; ++j)
            b[j] = *(const bf16x8*)&Bs[(wn + j * 16 + l15) * 32 + l4 * 8];
        #pragma unroll
        for (int i = 0; i < 4; ++i)
            #pragma unroll
            for (int j = 0; j < 4; ++j)
                acc[i][j] = __builtin_amdgcn_mfma_f32_16x16x32_bf16(
                    a[i], b[j], acc[i][j], 0, 0, 0);
    }

    const size_t zz = (size_t)blockIdx.z;
    if (mode == 2) {
        // Vt[b][c][s] = V[b][s][c] as bf16; m = b*2048 + s
        bf16_t* Co = (bf16_t*)Cout;
        #pragma unroll
        for (int i = 0; i < 4; ++i) {
            int mb = row0 + wm + i * 16 + l4 * 4;
            int b2 = mb >> 11, s = mb & 2047;
            #pragma unroll
            for (int j = 0; j < 4; ++j) {
                int c = col0 + wn + j * 16 + l15;
                float bv = bias[c];
                bf16x4 o;
                #pragma unroll
                for (int r = 0; r < 4; ++r) o[r] = (bf16_t)(acc[i][j][r] + bv);
                *(bf16x4*)&Co[((size_t)b2 * C_ + c) * S_ + s] = o;
            }
        }
    } else if (mode == 1) {
        bf16_t* Co = (bf16_t*)Cout + zz * sC;
        #pragma unroll
        for (int i = 0; i < 4; ++i)
            #pragma unroll
            for (int j = 0; j < 4; ++j) {
                int c = col0 + wn + j * 16 + l15;
                float bv = bias[c];
                #pragma unroll
                for (int r = 0; r < 4; ++r) {
                    int m = row0 + wm + i * 16 + l4 * 4 + r;
                    Co[(size_t)m * N + c] = (bf16_t)(acc[i][j][r] + bv);
                }
            }
    } else {
        float* Co = (float*)Cout + zz * sC;
        #pragma unroll
        for (int i = 0; i < 4; ++i)
            #pragma unroll
            for (int j = 0; j < 4; ++j) {
                int c = col0 + wn + j * 16 + l15;
                float bv = bias[c];
                #pragma unroll
                for (int r = 0; r < 4; ++r) {
                    int m = row0 + wm + i * 16 + l4 * 4 + r;
                    float v = acc[i][j][r] + bv;
                    if (mode == 3) v = mish_f(v);
                    Co[(size_t)m * N + c] = v;
                }
            }
    }
}

// -------------------------------------------------------------------------
// cv[bh,k,d] = sum_s tanh(t_mat[b,k,s]*wc[h]+bc[h]) * V[b,s,h*64+d]
// MFMA: A = tanh(c) bf16 (VALU-staged), B = Vt rows via global_load_lds.
// Block: 128 k-rows x 64 d; 4 waves of 32 rows; BK=32 over s.
// -------------------------------------------------------------------------
__global__ __launch_bounds__(256) void cv_mfma(
    const float* __restrict__ t_mat, const bf16_t* __restrict__ Vt,
    const float* __restrict__ wc, const float* __restrict__ bc,
    float* __restrict__ CV)
{
    const int bh = blockIdx.y, b = bh >> 4, h = bh & 15;
    const int k0 = blockIdx.x * 128;
    const int t = threadIdx.x;
    const int w = t >> 6, lane = t & 63;
    const int l15 = lane & 15, l4 = lane >> 4;

    __shared__ bf16_t As[128 * 32];
    __shared__ bf16_t Bs[64 * 32];

    const float wch = wc[h], bch = bc[h];
    const float* tb = t_mat + (size_t)b * S_ * S_ + (size_t)k0 * S_;
    const bf16_t* Vb = Vt + ((size_t)b * C_ + h * 64) * S_;

    const int rr = t >> 1, sp = (t & 1) * 16;   // A staging: row, s-offset
    const int vd = t >> 2, vse = (t & 3) * 8;   // B staging
    bf16_t* lB = Bs + (t & ~63) * 8;

    f32x4 acc[2][4] = {};

    for (int s0 = 0; s0 < S_; s0 += 32) {
        const float* trow = tb + (size_t)rr * S_ + s0 + sp;
        float4 v0 = *(const float4*)&trow[0];
        float4 v1 = *(const float4*)&trow[4];
        float4 v2 = *(const float4*)&trow[8];
        float4 v3 = *(const float4*)&trow[12];
        bf16x8 p0, p1;
        p0[0] = (bf16_t)tanh_fast(fmaf(v0.x, wch, bch));
        p0[1] = (bf16_t)tanh_fast(fmaf(v0.y, wch, bch));
        p0[2] = (bf16_t)tanh_fast(fmaf(v0.z, wch, bch));
        p0[3] = (bf16_t)tanh_fast(fmaf(v0.w, wch, bch));
        p0[4] = (bf16_t)tanh_fast(fmaf(v1.x, wch, bch));
        p0[5] = (bf16_t)tanh_fast(fmaf(v1.y, wch, bch));
        p0[6] = (bf16_t)tanh_fast(fmaf(v1.z, wch, bch));
        p0[7] = (bf16_t)tanh_fast(fmaf(v1.w, wch, bch));
        p1[0] = (bf16_t)tanh_fast(fmaf(v2.x, wch, bch));
        p1[1] = (bf16_t)tanh_fast(fmaf(v2.y, wch, bch));
        p1[2] = (bf16_t)tanh_fast(fmaf(v2.z, wch, bch));
        p1[3] = (bf16_t)tanh_fast(fmaf(v2.w, wch, bch));
        p1[4] = (bf16_t)tanh_fast(fmaf(v3.x, wch, bch));
        p1[5] = (bf16_t)tanh_fast(fmaf(v3.y, wch, bch));
        p1[6] = (bf16_t)tanh_fast(fmaf(v3.z, wch, bch));
        p1[7] = (bf16_t)tanh_fast(fmaf(v3.w, wch, bch));
        __syncthreads();
        gload16(Vb + (size_t)vd * S_ + s0 + vse, lB);
        *(bf16x8*)&As[rr * 32 + sp] = p0;
        *(bf16x8*)&As[rr * 32 + sp + 8] = p1;
        __syncthreads();
        bf16x8 a0 = *(const bf16x8*)&As[(w * 32 + l15) * 32 + l4 * 8];
        bf16x8 a1 = *(const bf16x8*)&As[(w * 32 + 16 + l15) * 32 + l4 * 8];
        #pragma unroll
        for (int j = 0; j < 4; ++j) {
            bf16x8 bb = *(const bf16x8*)&Bs[(j * 16 + l15) * 32 + l4 * 8];
            acc[0][j] = __builtin_amdgcn_mfma_f32_16x16x32_bf16(a0, bb, acc[0][j], 0, 0, 0);
            acc[1][j] = __builtin_amdgcn_mfma_f32_16x16x32_bf16(a1, bb, acc[1][j], 0, 0, 0);
        }
    }

    float* outp = CV + ((size_t)bh * S_ + k0) * D_;
    #pragma unroll
    for (int i = 0; i < 2; ++i)
        #pragma unroll
        for (int j = 0; j < 4; ++j)
            #pragma unroll
            for (int r = 0; r < 4; ++r)
                outp[(size_t)(w * 32 + i * 16 + l4 * 4 + r) * 64 + j * 16 + l15] =
                    acc[i][j][r];
}

// -------------------------------------------------------------------------
// M[bh,d',d] = sum_q Q[b,q,h*64+d'] * cv[bh,q,d]  (fp32, k-split atomics)
// -------------------------------------------------------------------------
__global__ __launch_bounds__(256) void qtcv_kernel(
    const float* __restrict__ Q, const float* __restrict__ CV,
    float* __restrict__ Mm)
{
    const int bh = blockIdx.y, b = bh >> 4, h = bh & 15;
    const int q0 = blockIdx.x * 256;
    const int t = threadIdx.x;
    const int tx = t & 15, ty = t >> 4;

    __shared__ float Qs[32][64];
    __shared__ float Cs[32][64];

    const float* Qb = Q + (size_t)b * S_ * C_ + h * 64;
    const float* Cb = CV + (size_t)bh * S_ * D_;

    const int r  = t >> 3;
    const int cc = (t & 7) << 3;

    float acc[4][4] = {};

    for (int qc = 0; qc < 256; qc += 32) {
        int q = q0 + qc + r;
        float4 a0 = *(const float4*)&Qb[(size_t)q * C_ + cc];
        float4 a1 = *(const float4*)&Qb[(size_t)q * C_ + cc + 4];
        float4 c0 = *(const float4*)&Cb[(size_t)q * D_ + cc];
        float4 c1 = *(const float4*)&Cb[(size_t)q * D_ + cc + 4];
        __syncthreads();
        *(float4*)&Qs[r][cc]     = a0;
        *(float4*)&Qs[r][cc + 4] = a1;
        *(float4*)&Cs[r][cc]     = c0;
        *(float4*)&Cs[r][cc + 4] = c1;
        __syncthreads();
        #pragma unroll
        for (int kk = 0; kk < 32; ++kk) {
            float av[4], bv[4];
            *(float4*)&av[0] = *(const float4*)&Qs[kk][ty * 4];
            *(float4*)&bv[0] = *(const float4*)&Cs[kk][tx * 4];
            #pragma unroll
            for (int i = 0; i < 4; ++i)
                #pragma unroll
                for (int j = 0; j < 4; ++j)
                    acc[i][j] = fmaf(av[i], bv[j], acc[i][j]);
        }
    }

    float* mp = Mm + (size_t)bh * 64 * 64;
    #pragma unroll
    for (int i = 0; i < 4; ++i)
        #pragma unroll
        for (int j = 0; j < 4; ++j)
            atomicAdd(&mp[(size_t)(ty * 4 + i) * 64 + tx * 4 + j], acc[i][j]);
}

// -------------------------------------------------------------------------
// Wefft[b, co, h*64+d'] = (1/8) * sum_d M[bh,d',d] * wf[h*64+d, co]  (bf16)
// -------------------------------------------------------------------------
__global__ __launch_bounds__(256) void weff_kernel(
    const float* __restrict__ Mm, const float* __restrict__ wf,
    bf16_t* __restrict__ Wefft)
{
    const int b = blockIdx.z, h = blockIdx.y;
    const int co0 = blockIdx.x * 64;
    const int t = threadIdx.x;
    const int tx = t & 15, ty = t >> 4;

    __shared__ float Ms[64][64];
    __shared__ float Ws[64][64];

    const float* Mb = Mm + (size_t)(b * H_ + h) * 64 * 64;

    const int r  = t >> 2;
    const int c4 = (t & 3) << 2;

    #pragma unroll
    for (int rep = 0; rep < 4; ++rep) {
        int col = c4 + rep * 16;
        float4 m4 = *(const float4*)&Mb[(size_t)r * 64 + col];
        Ms[col + 0][r] = m4.x; Ms[col + 1][r] = m4.y;
        Ms[col + 2][r] = m4.z; Ms[col + 3][r] = m4.w;
        float4 w4 = *(const float4*)&wf[(size_t)(h * 64 + r) * C_ + co0 + col];
        *(float4*)&Ws[r][col] = w4;
    }
    __syncthreads();

    float acc[4][4] = {};
    #pragma unroll
    for (int kk = 0; kk < 64; ++kk) {
        float av[4], bv[4];
        *(float4*)&av[0] = *(const float4*)&Ms[kk][ty * 4];
        *(float4*)&bv[0] = *(const float4*)&Ws[kk][tx * 4];
        #pragma unroll
        for (int i = 0; i < 4; ++i)
            #pragma unroll
            for (int j = 0; j < 4; ++j)
                acc[i][j] = fmaf(av[i], bv[j], acc[i][j]);
    }

    bf16_t* wp = Wefft + (size_t)b * C_ * C_;
    #pragma unroll
    for (int i = 0; i < 4; ++i)
        #pragma unroll
        for (int j = 0; j < 4; ++j)
            wp[(size_t)(co0 + tx * 4 + j) * C_ + h * 64 + ty * 4 + i] =
                (bf16_t)(acc[i][j] * 0.125f);  // fold 1/sqrt(D)=1/8
}

// -------------------------------------------------------------------------
extern "C" void kernel_launch(void* const* d_in, const int* in_sizes, int n_in,
                              void* d_out, int out_size, void* d_ws, size_t ws_size,
                              hipStream_t stream) {
    const float* x     = (const float*)d_in[0];
    const float* y     = (const float*)d_in[1];
    const float* t_mat = (const float*)d_in[2];
    const float* wq    = (const float*)d_in[3];
    const float* bq    = (const float*)d_in[4];
    const float* wk    = (const float*)d_in[5];
    const float* bk    = (const float*)d_in[6];
    const float* wv    = (const float*)d_in[7];
    const float* bv    = (const float*)d_in[8];
    const float* wc    = (const float*)d_in[9];
    const float* bc    = (const float*)d_in[10];
    const float* wf    = (const float*)d_in[11];
    const float* bf    = (const float*)d_in[12];
    float* out = (float*)d_out;

    // workspace layout (bytes)
    char* p = (char*)d_ws;
    bf16_t* ybf  = (bf16_t*)p;  p += (size_t)B_ * S_ * C_ * 2;   // 8 MB
    bf16_t* xbf  = (bf16_t*)p;  p += (size_t)B_ * S_ * C_ * 2;   // 8 MB
    bf16_t* wqt  = (bf16_t*)p;  p += (size_t)C_ * C_ * 2;        // 2 MB
    bf16_t* wkt  = (bf16_t*)p;  p += (size_t)C_ * C_ * 2;
    bf16_t* wvt  = (bf16_t*)p;  p += (size_t)C_ * C_ * 2;
    float*  Qm   = (float*)p;   p += (size_t)B_ * S_ * C_ * 4;   // 16 MB
    bf16_t* Kbf  = (bf16_t*)p;  p += (size_t)B_ * S_ * C_ * 2;   // 8 MB
    bf16_t* Vt   = (bf16_t*)p;  p += (size_t)B_ * C_ * S_ * 2;   // 8 MB
    float*  Mm   = (float*)p;   p += (size_t)B_ * H_ * 64 * 64 * 4;
    bf16_t* Weft = (bf16_t*)p;  p += (size_t)B_ * C_ * C_ * 2;   // 4 MB
    // CVm aliases ybf+xbf (dead after projections; cv runs after all projs)
    float* CVm = (float*)ybf;   // needs 16 MB == ybf(8) + xbf(8)

    hipMemsetAsync(Mm, 0, (size_t)B_ * H_ * 64 * 64 * sizeof(float), stream);

    dim3 blk(256);

    // fp32 -> bf16 conversions
    cvt2_bf16<<<dim3((B_ * S_ * C_) / (256 * 8), 2), blk, 0, stream>>>(
        y, ybf, x, xbf);
    wtrans_bf16<<<dim3(16, 16, 3), blk, 0, stream>>>(wq, wk, wv, wqt, wkt, wvt);

    // projections (M=4096, N=1024, K=1024)
    dim3 gproj(C_ / 128, (B_ * S_) / 128, 1);
    mfma_gemm<<<gproj, blk, 0, stream>>>(ybf, wqt, bq, Qm,
        B_ * S_, C_, C_, 0, 0, 0, 0);            // Q fp32
    mfma_gemm<<<gproj, blk, 0, stream>>>(xbf, wkt, bk, Kbf,
        B_ * S_, C_, C_, 0, 0, 0, 1);            // K bf16
    mfma_gemm<<<gproj, blk, 0, stream>>>(ybf, wvt, bv, Vt,
        B_ * S_, C_, C_, 0, 0, 0, 2);            // V bf16 transposed

    // cv = tanh(t_mat*wc+bc) @ V per head (MFMA)
    cv_mfma<<<dim3(S_ / 128, B_ * H_), blk, 0, stream>>>(t_mat, Vt, wc, bc, CVm);

    // M = Q^T @ cv per head (64x64)
    qtcv_kernel<<<dim3(8, B_ * H_), blk, 0, stream>>>(Qm, CVm, Mm);

    // Weff^T (bf16), with 1/8 folded
    weff_kernel<<<dim3(C_ / 64, H_, B_), blk, 0, stream>>>(Mm, wf, Weft);

    // out = mish(K @ Weff + bf), per batch
    mfma_gemm<<<dim3(C_ / 128, S_ / 128, B_), blk, 0, stream>>>(
        Kbf, Weft, bf, out, S_, C_, C_,
        (long)S_ * C_, (long)C_ * C_, (long)S_ * C_, 3);
}

// Round 3
// 295.274 us; speedup vs baseline: 3.3472x; 1.4412x over previous
//
#include <hip/hip_runtime.h>
#include <math.h>

#define B_ 2
#define S_ 2048
#define C_ 1024
#define H_ 16
#define D_ 64

typedef __bf16 bf16_t;
typedef __attribute__((ext_vector_type(8))) __bf16 bf16x8;
typedef __attribute__((ext_vector_type(4))) __bf16 bf16x4;
typedef __attribute__((ext_vector_type(4))) float f32x4;

__device__ __forceinline__ void gload16(const void* g, void* l) {
    __builtin_amdgcn_global_load_lds(
        (const __attribute__((address_space(1))) unsigned int*)g,
        (__attribute__((address_space(3))) unsigned int*)l, 16, 0, 0);
}

__device__ __forceinline__ float tanh_fast(float z) {
    z = fminf(fmaxf(z, -12.f), 12.f);
    float e = __expf(2.f * z);
    return 1.f - __fdividef(2.f, e + 1.f);
}

__device__ __forceinline__ float mish_f(float x) {
    float sp = (x > 15.f) ? x : log1pf(__expf(x));
    return x * tanh_fast(sp);
}

// tanh(t*w+b) with 2/ln2 pre-folded into w2,b2: 1 - 2*rcp(exp2(t*w2+b2)+1)
__device__ __forceinline__ float tanh_folded(float t, float w2, float b2) {
    float e = __builtin_amdgcn_exp2f(fmaf(t, w2, b2));
    float r = __builtin_amdgcn_rcpf(e + 1.f);
    return fmaf(-2.f, r, 1.f);
}

// -------------------------------------------------------------------------
// Elementwise fp32 -> bf16 (two tensors via blockIdx.y)
// -------------------------------------------------------------------------
__global__ __launch_bounds__(256) void cvt2_bf16(
    const float* __restrict__ a, bf16_t* __restrict__ oa,
    const float* __restrict__ b, bf16_t* __restrict__ ob)
{
    size_t i = ((size_t)blockIdx.x * 256 + threadIdx.x) * 8;
    const float* in = blockIdx.y ? b : a;
    bf16_t* out = blockIdx.y ? ob : oa;
    float4 u = *(const float4*)&in[i];
    float4 v = *(const float4*)&in[i + 4];
    bf16x8 o;
    o[0] = (bf16_t)u.x; o[1] = (bf16_t)u.y; o[2] = (bf16_t)u.z; o[3] = (bf16_t)u.w;
    o[4] = (bf16_t)v.x; o[5] = (bf16_t)v.y; o[6] = (bf16_t)v.z; o[7] = (bf16_t)v.w;
    *(bf16x8*)&out[i] = o;
}

// -------------------------------------------------------------------------
// Transpose-convert weights [K,N] fp32 -> [N,K] bf16 (3 weights via z)
// -------------------------------------------------------------------------
__global__ __launch_bounds__(256) void wtrans_bf16(
    const float* __restrict__ w0, const float* __restrict__ w1,
    const float* __restrict__ w2,
    bf16_t* __restrict__ o0, bf16_t* __restrict__ o1, bf16_t* __restrict__ o2)
{
    const float* in = blockIdx.z == 0 ? w0 : (blockIdx.z == 1 ? w1 : w2);
    bf16_t* out = blockIdx.z == 0 ? o0 : (blockIdx.z == 1 ? o1 : o2);
    __shared__ float ts[64][65];
    const int t = threadIdx.x;
    const int k0 = blockIdx.y * 64, n0 = blockIdx.x * 64;
    const int r = t >> 2, c0 = (t & 3) * 16;
    #pragma unroll
    for (int j = 0; j < 16; j += 4) {
        float4 v = *(const float4*)&in[(size_t)(k0 + r) * C_ + n0 + c0 + j];
        ts[c0 + j + 0][r] = v.x; ts[c0 + j + 1][r] = v.y;
        ts[c0 + j + 2][r] = v.z; ts[c0 + j + 3][r] = v.w;
    }
    __syncthreads();
    #pragma unroll
    for (int g = 0; g < 2; ++g) {
        bf16x8 o;
        #pragma unroll
        for (int e = 0; e < 8; ++e) o[e] = (bf16_t)ts[r][c0 + g * 8 + e];
        *(bf16x8*)&out[(size_t)(n0 + r) * C_ + k0 + c0 + g * 8] = o;
    }
}

// -------------------------------------------------------------------------
// Fused QKV projection, one launch. z=0: y@wq -> Qt (transposed bf16),
// z=1: x@wk -> Kb (row-major bf16), z=2: y@wv -> Vt (transposed bf16).
// 128x128 tile, BK=32, 16x16x32 MFMA, global_load_lds staging.
// grid (8, 32, 3)
// -------------------------------------------------------------------------
__global__ __launch_bounds__(256) void qkv_proj(
    const bf16_t* __restrict__ ybf, const bf16_t* __restrict__ xbf,
    const bf16_t* __restrict__ wqt, const bf16_t* __restrict__ wkt,
    const bf16_t* __restrict__ wvt,
    const float* __restrict__ bq, const float* __restrict__ bk,
    const float* __restrict__ bv,
    bf16_t* __restrict__ Qt, bf16_t* __restrict__ Kb, bf16_t* __restrict__ Vt)
{
    const int z = blockIdx.z;
    const bf16_t* A  = (z == 1) ? xbf : ybf;
    const bf16_t* Bt = (z == 0) ? wqt : (z == 1) ? wkt : wvt;
    const float* bias = (z == 0) ? bq : (z == 1) ? bk : bv;
    const int K = C_;

    __shared__ bf16_t As[128 * 32];
    __shared__ bf16_t Bs[128 * 32];

    const int t = threadIdx.x;
    const int w = t >> 6, lane = t & 63;
    const int wm = (w >> 1) * 64, wn = (w & 1) * 64;
    const int l15 = lane & 15, l4 = lane >> 4;
    const int row0 = blockIdx.y * 128, col0 = blockIdx.x * 128;

    const int sr = t >> 2, sk = (t & 3) * 8;
    const bf16_t* gA = A + (size_t)(row0 + sr) * K + sk;
    const bf16_t* gB = Bt + (size_t)(col0 + sr) * K + sk;
    bf16_t* lA = As + (t & ~63) * 8;
    bf16_t* lB = Bs + (t & ~63) * 8;

    f32x4 acc[4][4] = {};

    for (int k0 = 0; k0 < K; k0 += 32) {
        __syncthreads();
        gload16(gA + k0, lA);
        gload16(gA + k0 + (size_t)64 * K, lA + 2048);
        gload16(gB + k0, lB);
        gload16(gB + k0 + (size_t)64 * K, lB + 2048);
        __syncthreads();
        bf16x8 a[4], b[4];
        #pragma unroll
        for (int i = 0; i < 4; ++i)
            a[i] = *(const bf16x8*)&As[(wm + i * 16 + l15) * 32 + l4 * 8];
        #pragma unroll
        for (int j = 0; j < 4; ++j)
            b[j] = *(const bf16x8*)&Bs[(wn + j * 16 + l15) * 32 + l4 * 8];
        #pragma unroll
        for (int i = 0; i < 4; ++i)
            #pragma unroll
            for (int j = 0; j < 4; ++j)
                acc[i][j] = __builtin_amdgcn_mfma_f32_16x16x32_bf16(
                    a[i], b[j], acc[i][j], 0, 0, 0);
    }

    if (z != 1) {
        // transposed store: T[b][c][s], m = b*2048+s
        bf16_t* To = (z == 0) ? Qt : Vt;
        #pragma unroll
        for (int i = 0; i < 4; ++i) {
            int mb = row0 + wm + i * 16 + l4 * 4;
            int b2 = mb >> 11, s = mb & 2047;
            #pragma unroll
            for (int j = 0; j < 4; ++j) {
                int c = col0 + wn + j * 16 + l15;
                float bv2 = bias[c];
                bf16x4 o;
                #pragma unroll
                for (int r = 0; r < 4; ++r) o[r] = (bf16_t)(acc[i][j][r] + bv2);
                *(bf16x4*)&To[((size_t)b2 * C_ + c) * S_ + s] = o;
            }
        }
    } else {
        #pragma unroll
        for (int i = 0; i < 4; ++i)
            #pragma unroll
            for (int j = 0; j < 4; ++j) {
                int c = col0 + wn + j * 16 + l15;
                float bv2 = bias[c];
                #pragma unroll
                for (int r = 0; r < 4; ++r) {
                    int m = row0 + wm + i * 16 + l4 * 4 + r;
                    Kb[(size_t)m * C_ + c] = (bf16_t)(acc[i][j][r] + bv2);
                }
            }
    }
}

// -------------------------------------------------------------------------
// cv partials: CVpt[p][bh][d][q] = sum_{s in p-range} tanh(...)*V[s,d]
// grid (S/128=16, P=4, BH=32) = 2048 blocks. Block: 128 q-rows x 64 d,
// s-range of 512 per partial.
// -------------------------------------------------------------------------
__global__ __launch_bounds__(256) void cv_mfma(
    const float* __restrict__ t_mat, const bf16_t* __restrict__ Vt,
    const float* __restrict__ wc, const float* __restrict__ bc,
    bf16_t* __restrict__ CVpt)
{
    const int bh = blockIdx.z, b = bh >> 4, h = bh & 15;
    const int q0 = blockIdx.x * 128;
    const int p = blockIdx.y;
    const int t = threadIdx.x;
    const int w = t >> 6, lane = t & 63;
    const int l15 = lane & 15, l4 = lane >> 4;

    __shared__ bf16_t As[128 * 32];
    __shared__ bf16_t Bs[64 * 32];

    const float LOG2E2 = 2.8853900817779268f;  // 2/ln2
    const float wch2 = wc[h] * LOG2E2, bch2 = bc[h] * LOG2E2;
    const float* tb = t_mat + (size_t)b * S_ * S_ + (size_t)q0 * S_;
    const bf16_t* Vb = Vt + ((size_t)b * C_ + h * 64) * S_;

    const int rr = t >> 1, sp = (t & 1) * 16;   // A staging: row, s-offset
    const int vd = t >> 2, vse = (t & 3) * 8;   // B staging
    bf16_t* lB = Bs + (t & ~63) * 8;

    f32x4 acc[2][4] = {};

    const int s_beg = p * 512, s_end = s_beg + 512;
    for (int s0 = s_beg; s0 < s_end; s0 += 32) {
        const float* trow = tb + (size_t)rr * S_ + s0 + sp;
        float4 v0 = *(const float4*)&trow[0];
        float4 v1 = *(const float4*)&trow[4];
        float4 v2 = *(const float4*)&trow[8];
        float4 v3 = *(const float4*)&trow[12];
        bf16x8 p0, p1;
        p0[0] = (bf16_t)tanh_folded(v0.x, wch2, bch2);
        p0[1] = (bf16_t)tanh_folded(v0.y, wch2, bch2);
        p0[2] = (bf16_t)tanh_folded(v0.z, wch2, bch2);
        p0[3] = (bf16_t)tanh_folded(v0.w, wch2, bch2);
        p0[4] = (bf16_t)tanh_folded(v1.x, wch2, bch2);
        p0[5] = (bf16_t)tanh_folded(v1.y, wch2, bch2);
        p0[6] = (bf16_t)tanh_folded(v1.z, wch2, bch2);
        p0[7] = (bf16_t)tanh_folded(v1.w, wch2, bch2);
        p1[0] = (bf16_t)tanh_folded(v2.x, wch2, bch2);
        p1[1] = (bf16_t)tanh_folded(v2.y, wch2, bch2);
        p1[2] = (bf16_t)tanh_folded(v2.z, wch2, bch2);
        p1[3] = (bf16_t)tanh_folded(v2.w, wch2, bch2);
        p1[4] = (bf16_t)tanh_folded(v3.x, wch2, bch2);
        p1[5] = (bf16_t)tanh_folded(v3.y, wch2, bch2);
        p1[6] = (bf16_t)tanh_folded(v3.z, wch2, bch2);
        p1[7] = (bf16_t)tanh_folded(v3.w, wch2, bch2);
        __syncthreads();
        gload16(Vb + (size_t)vd * S_ + s0 + vse, lB);
        *(bf16x8*)&As[rr * 32 + sp] = p0;
        *(bf16x8*)&As[rr * 32 + sp + 8] = p1;
        __syncthreads();
        bf16x8 a0 = *(const bf16x8*)&As[(w * 32 + l15) * 32 + l4 * 8];
        bf16x8 a1 = *(const bf16x8*)&As[(w * 32 + 16 + l15) * 32 + l4 * 8];
        #pragma unroll
        for (int j = 0; j < 4; ++j) {
            bf16x8 bb = *(const bf16x8*)&Bs[(j * 16 + l15) * 32 + l4 * 8];
            acc[0][j] = __builtin_amdgcn_mfma_f32_16x16x32_bf16(a0, bb, acc[0][j], 0, 0, 0);
            acc[1][j] = __builtin_amdgcn_mfma_f32_16x16x32_bf16(a1, bb, acc[1][j], 0, 0, 0);
        }
    }

    // transposed bf16 store: CVpt[p][bh][d][q]
    bf16_t* outp = CVpt + ((size_t)(p * 32 + bh) * 64) * S_;
    #pragma unroll
    for (int i = 0; i < 2; ++i) {
        int q = q0 + w * 32 + i * 16 + l4 * 4;
        #pragma unroll
        for (int j = 0; j < 4; ++j) {
            int d = j * 16 + l15;
            bf16x4 o;
            #pragma unroll
            for (int r = 0; r < 4; ++r) o[r] = (bf16_t)acc[i][j][r];
            *(bf16x4*)&outp[(size_t)d * S_ + q] = o;
        }
    }
}

// -------------------------------------------------------------------------
// M[bh,d',d] += sum_{p,q-range} Qt[b,h*64+d',q] * CVpt[p,bh,d,q]   (MFMA)
// grid (16 q-splits of 128, 32 bh) = 512 blocks; atomicAdd fp32 into Mm.
// -------------------------------------------------------------------------
__global__ __launch_bounds__(256) void qtcv_mfma(
    const bf16_t* __restrict__ Qt, const bf16_t* __restrict__ CVpt,
    float* __restrict__ Mm)
{
    const int bh = blockIdx.y, b = bh >> 4, h = bh & 15;
    const int q0 = blockIdx.x * 128;
    const int t = threadIdx.x;
    const int w = t >> 6, lane = t & 63;
    const int wm = (w >> 1) * 32, wn = (w & 1) * 32;
    const int l15 = lane & 15, l4 = lane >> 4;

    __shared__ bf16_t As[64 * 32];
    __shared__ bf16_t Bs[64 * 32];

    const bf16_t* Aq = Qt + ((size_t)b * C_ + h * 64) * S_;

    const int sr = t >> 2, sk = (t & 3) * 8;
    bf16_t* lA = As + (t & ~63) * 8;
    bf16_t* lB = Bs + (t & ~63) * 8;

    f32x4 acc[2][2] = {};

    for (int qc = 0; qc < 128; qc += 32) {
        const int q = q0 + qc;
        __syncthreads();  // protect As from previous reads
        gload16(Aq + (size_t)sr * S_ + q + sk, lA);
        #pragma unroll
        for (int p = 0; p < 4; ++p) {
            const bf16_t* Bq = CVpt + ((size_t)(p * 32 + bh) * 64) * S_;
            __syncthreads();  // protect Bs from previous reads
            gload16(Bq + (size_t)sr * S_ + q + sk, lB);
            __syncthreads();  // staged data visible (drains vmcnt)
            bf16x8 a0 = *(const bf16x8*)&As[(wm + l15) * 32 + l4 * 8];
            bf16x8 a1 = *(const bf16x8*)&As[(wm + 16 + l15) * 32 + l4 * 8];
            bf16x8 b0 = *(const bf16x8*)&Bs[(wn + l15) * 32 + l4 * 8];
            bf16x8 b1 = *(const bf16x8*)&Bs[(wn + 16 + l15) * 32 + l4 * 8];
            acc[0][0] = __builtin_amdgcn_mfma_f32_16x16x32_bf16(a0, b0, acc[0][0], 0, 0, 0);
            acc[0][1] = __builtin_amdgcn_mfma_f32_16x16x32_bf16(a0, b1, acc[0][1], 0, 0, 0);
            acc[1][0] = __builtin_amdgcn_mfma_f32_16x16x32_bf16(a1, b0, acc[1][0], 0, 0, 0);
            acc[1][1] = __builtin_amdgcn_mfma_f32_16x16x32_bf16(a1, b1, acc[1][1], 0, 0, 0);
        }
    }

    float* mp = Mm + (size_t)bh * 64 * 64;
    #pragma unroll
    for (int i = 0; i < 2; ++i)
        #pragma unroll
        for (int j = 0; j < 2; ++j)
            #pragma unroll
            for (int r = 0; r < 4; ++r)
                atomicAdd(&mp[(size_t)(wm + i * 16 + l4 * 4 + r) * 64 +
                              wn + j * 16 + l15], acc[i][j][r]);
}

// -------------------------------------------------------------------------
// Wefft[b, co, h*64+d'] = (1/8) * sum_d M[bh,d',d] * wf[h*64+d, co]  (bf16)
// -------------------------------------------------------------------------
__global__ __launch_bounds__(256) void weff_kernel(
    const float* __restrict__ Mm, const float* __restrict__ wf,
    bf16_t* __restrict__ Wefft)
{
    const int b = blockIdx.z, h = blockIdx.y;
    const int co0 = blockIdx.x * 64;
    const int t = threadIdx.x;
    const int tx = t & 15, ty = t >> 4;

    __shared__ float Ms[64][64];
    __shared__ float Ws[64][64];

    const float* Mb = Mm + (size_t)(b * H_ + h) * 64 * 64;

    const int r  = t >> 2;
    const int c4 = (t & 3) << 2;

    #pragma unroll
    for (int rep = 0; rep < 4; ++rep) {
        int col = c4 + rep * 16;
        float4 m4 = *(const float4*)&Mb[(size_t)r * 64 + col];
        Ms[col + 0][r] = m4.x; Ms[col + 1][r] = m4.y;
        Ms[col + 2][r] = m4.z; Ms[col + 3][r] = m4.w;
        float4 w4 = *(const float4*)&wf[(size_t)(h * 64 + r) * C_ + co0 + col];
        *(float4*)&Ws[r][col] = w4;
    }
    __syncthreads();

    float acc[4][4] = {};
    #pragma unroll
    for (int kk = 0; kk < 64; ++kk) {
        float av[4], bv2[4];
        *(float4*)&av[0] = *(const float4*)&Ms[kk][ty * 4];
        *(float4*)&bv2[0] = *(const float4*)&Ws[kk][tx * 4];
        #pragma unroll
        for (int i = 0; i < 4; ++i)
            #pragma unroll
            for (int j = 0; j < 4; ++j)
                acc[i][j] = fmaf(av[i], bv2[j], acc[i][j]);
    }

    bf16_t* wp = Wefft + (size_t)b * C_ * C_;
    #pragma unroll
    for (int i = 0; i < 4; ++i)
        #pragma unroll
        for (int j = 0; j < 4; ++j)
            wp[(size_t)(co0 + tx * 4 + j) * C_ + h * 64 + ty * 4 + i] =
                (bf16_t)(acc[i][j] * 0.125f);  // fold 1/sqrt(D)=1/8
}

// -------------------------------------------------------------------------
// out = mish(Kb[b] @ Wefft[b]^T + bf), fp32 out. grid (8, 16, 2)
// -------------------------------------------------------------------------
__global__ __launch_bounds__(256) void final_gemm(
    const bf16_t* __restrict__ Kb, const bf16_t* __restrict__ Weft,
    const float* __restrict__ bias, float* __restrict__ out)
{
    const int z = blockIdx.z;
    const bf16_t* A  = Kb + (size_t)z * S_ * C_;
    const bf16_t* Bt = Weft + (size_t)z * C_ * C_;
    float* Co = out + (size_t)z * S_ * C_;
    const int K = C_;

    __shared__ bf16_t As[128 * 32];
    __shared__ bf16_t Bs[128 * 32];

    const int t = threadIdx.x;
    const int w = t >> 6, lane = t & 63;
    const int wm = (w >> 1) * 64, wn = (w & 1) * 64;
    const int l15 = lane & 15, l4 = lane >> 4;
    const int row0 = blockIdx.y * 128, col0 = blockIdx.x * 128;

    const int sr = t >> 2, sk = (t & 3) * 8;
    const bf16_t* gA = A + (size_t)(row0 + sr) * K + sk;
    const bf16_t* gB = Bt + (size_t)(col0 + sr) * K + sk;
    bf16_t* lA = As + (t & ~63) * 8;
    bf16_t* lB = Bs + (t & ~63) * 8;

    f32x4 acc[4][4] = {};

    for (int k0 = 0; k0 < K; k0 += 32) {
        __syncthreads();
        gload16(gA + k0, lA);
        gload16(gA + k0 + (size_t)64 * K, lA + 2048);
        gload16(gB + k0, lB);
        gload16(gB + k0 + (size_t)64 * K, lB + 2048);
        __syncthreads();
        bf16x8 a[4], b[4];
        #pragma unroll
        for (int i = 0; i < 4; ++i)
            a[i] = *(const bf16x8*)&As[(wm + i * 16 + l15) * 32 + l4 * 8];
        #pragma unroll
        for (int j = 0; j < 4; ++j)
            b[j] = *(const bf16x8*)&Bs[(wn + j * 16 + l15) * 32 + l4 * 8];
        #pragma unroll
        for (int i = 0; i < 4; ++i)
            #pragma unroll
            for (int j = 0; j < 4; ++j)
                acc[i][j] = __builtin_amdgcn_mfma_f32_16x16x32_bf16(
                    a[i], b[j], acc[i][j], 0, 0, 0);
    }

    #pragma unroll
    for (int i = 0; i < 4; ++i)
        #pragma unroll
        for (int j = 0; j < 4; ++j) {
            int c = col0 + wn + j * 16 + l15;
            float bv2 = bias[c];
            #pragma unroll
            for (int r = 0; r < 4; ++r) {
                int m = row0 + wm + i * 16 + l4 * 4 + r;
                Co[(size_t)m * C_ + c] = mish_f(acc[i][j][r] + bv2);
            }
        }
}

// -------------------------------------------------------------------------
extern "C" void kernel_launch(void* const* d_in, const int* in_sizes, int n_in,
                              void* d_out, int out_size, void* d_ws, size_t ws_size,
                              hipStream_t stream) {
    const float* x     = (const float*)d_in[0];
    const float* y     = (const float*)d_in[1];
    const float* t_mat = (const float*)d_in[2];
    const float* wq    = (const float*)d_in[3];
    const float* bq    = (const float*)d_in[4];
    const float* wk    = (const float*)d_in[5];
    const float* bk    = (const float*)d_in[6];
    const float* wv    = (const float*)d_in[7];
    const float* bv    = (const float*)d_in[8];
    const float* wc    = (const float*)d_in[9];
    const float* bc    = (const float*)d_in[10];
    const float* wf    = (const float*)d_in[11];
    const float* bf    = (const float*)d_in[12];
    float* out = (float*)d_out;

    // workspace layout (byte offsets); CVpt aliases ybf..wvt + fresh tail
    char* base = (char*)d_ws;
    bf16_t* Qt   = (bf16_t*)(base + 0);          //  8 MiB  [b][c][s]
    bf16_t* Kb   = (bf16_t*)(base + 8388608);    //  8 MiB  [b*s][c]
    bf16_t* Vt   = (bf16_t*)(base + 16777216);   //  8 MiB  [b][c][s]
    float*  Mm   = (float*) (base + 25165824);   //  0.5 MiB
    bf16_t* Weft = (bf16_t*)(base + 25690112);   //  4 MiB  [b][co][cin]
    bf16_t* ybf  = (bf16_t*)(base + 29884416);   //  8 MiB
    bf16_t* xbf  = (bf16_t*)(base + 38273024);   //  8 MiB
    bf16_t* wqt  = (bf16_t*)(base + 46661632);   //  2 MiB
    bf16_t* wkt  = (bf16_t*)(base + 48758784);   //  2 MiB
    bf16_t* wvt  = (bf16_t*)(base + 50855936);   //  2 MiB (end 52,953,088)
    bf16_t* CVpt = (bf16_t*)(base + 29884416);   // 32 MiB [p][bh][d][q]
                                                 // (aliases ybf.., end 63,438,848)

    hipMemsetAsync(Mm, 0, (size_t)B_ * H_ * 64 * 64 * sizeof(float), stream);

    dim3 blk(256);

    cvt2_bf16<<<dim3((B_ * S_ * C_) / (256 * 8), 2), blk, 0, stream>>>(
        y, ybf, x, xbf);
    wtrans_bf16<<<dim3(16, 16, 3), blk, 0, stream>>>(wq, wk, wv, wqt, wkt, wvt);

    // fused QKV projections (768 blocks)
    qkv_proj<<<dim3(C_ / 128, (B_ * S_) / 128, 3), blk, 0, stream>>>(
        ybf, xbf, wqt, wkt, wvt, bq, bk, bv, Qt, Kb, Vt);

    // cv partials (2048 blocks)
    cv_mfma<<<dim3(S_ / 128, 4, B_ * H_), blk, 0, stream>>>(
        t_mat, Vt, wc, bc, CVpt);

    // M = Q^T @ cv (MFMA over partials, 512 blocks)
    qtcv_mfma<<<dim3(16, B_ * H_), blk, 0, stream>>>(Qt, CVpt, Mm);

    // Weff^T (bf16), 1/8 folded
    weff_kernel<<<dim3(C_ / 64, H_, B_), blk, 0, stream>>>(Mm, wf, Weft);

    // out = mish(K @ Weff + bf)
    final_gemm<<<dim3(C_ / 128, S_ / 128, B_), blk, 0, stream>>>(
        Kb, Weft, bf, out);
}

// Round 4
// 277.284 us; speedup vs baseline: 3.5644x; 1.0649x over previous
//
#include <hip/hip_runtime.h>
#include <math.h>

#define B_ 2
#define S_ 2048
#define C_ 1024
#define H_ 16
#define D_ 64

typedef __bf16 bf16_t;
typedef __attribute__((ext_vector_type(8))) __bf16 bf16x8;
typedef __attribute__((ext_vector_type(4))) __bf16 bf16x4;
typedef __attribute__((ext_vector_type(4))) float f32x4;

__device__ __forceinline__ void gload16(const void* g, void* l) {
    __builtin_amdgcn_global_load_lds(
        (const __attribute__((address_space(1))) unsigned int*)g,
        (__attribute__((address_space(3))) unsigned int*)l, 16, 0, 0);
}

__device__ __forceinline__ float tanh_fast(float z) {
    z = fminf(fmaxf(z, -12.f), 12.f);
    float e = __expf(2.f * z);
    return 1.f - __fdividef(2.f, e + 1.f);
}

__device__ __forceinline__ float mish_f(float x) {
    float sp = (x > 15.f) ? x : log1pf(__expf(x));
    return x * tanh_fast(sp);
}

// tanh(t*w+b) with 2/ln2 pre-folded into w2,b2: 1 - 2*rcp(exp2(t*w2+b2)+1)
__device__ __forceinline__ float tanh_folded(float t, float w2, float b2) {
    float e = __builtin_amdgcn_exp2f(fmaf(t, w2, b2));
    float r = __builtin_amdgcn_rcpf(e + 1.f);
    return fmaf(-2.f, r, 1.f);
}

// -------------------------------------------------------------------------
// Elementwise fp32 -> bf16 (two tensors via blockIdx.y)
// -------------------------------------------------------------------------
__global__ __launch_bounds__(256) void cvt2_bf16(
    const float* __restrict__ a, bf16_t* __restrict__ oa,
    const float* __restrict__ b, bf16_t* __restrict__ ob)
{
    size_t i = ((size_t)blockIdx.x * 256 + threadIdx.x) * 8;
    const float* in = blockIdx.y ? b : a;
    bf16_t* out = blockIdx.y ? ob : oa;
    float4 u = *(const float4*)&in[i];
    float4 v = *(const float4*)&in[i + 4];
    bf16x8 o;
    o[0] = (bf16_t)u.x; o[1] = (bf16_t)u.y; o[2] = (bf16_t)u.z; o[3] = (bf16_t)u.w;
    o[4] = (bf16_t)v.x; o[5] = (bf16_t)v.y; o[6] = (bf16_t)v.z; o[7] = (bf16_t)v.w;
    *(bf16x8*)&out[i] = o;
}

// -------------------------------------------------------------------------
// Transpose-convert weights [K,N] fp32 -> [N,K] bf16 (3 weights via z)
// -------------------------------------------------------------------------
__global__ __launch_bounds__(256) void wtrans_bf16(
    const float* __restrict__ w0, const float* __restrict__ w1,
    const float* __restrict__ w2,
    bf16_t* __restrict__ o0, bf16_t* __restrict__ o1, bf16_t* __restrict__ o2)
{
    const float* in = blockIdx.z == 0 ? w0 : (blockIdx.z == 1 ? w1 : w2);
    bf16_t* out = blockIdx.z == 0 ? o0 : (blockIdx.z == 1 ? o1 : o2);
    __shared__ float ts[64][65];
    const int t = threadIdx.x;
    const int k0 = blockIdx.y * 64, n0 = blockIdx.x * 64;
    const int r = t >> 2, c0 = (t & 3) * 16;
    #pragma unroll
    for (int j = 0; j < 16; j += 4) {
        float4 v = *(const float4*)&in[(size_t)(k0 + r) * C_ + n0 + c0 + j];
        ts[c0 + j + 0][r] = v.x; ts[c0 + j + 1][r] = v.y;
        ts[c0 + j + 2][r] = v.z; ts[c0 + j + 3][r] = v.w;
    }
    __syncthreads();
    #pragma unroll
    for (int g = 0; g < 2; ++g) {
        bf16x8 o;
        #pragma unroll
        for (int e = 0; e < 8; ++e) o[e] = (bf16_t)ts[r][c0 + g * 8 + e];
        *(bf16x8*)&out[(size_t)(n0 + r) * C_ + k0 + c0 + g * 8] = o;
    }
}

// -------------------------------------------------------------------------
// Fused QKV projection, one launch. z=0: y@wq -> Qt (transposed bf16),
// z=1: x@wk -> Kb (row-major bf16), z=2: y@wv -> Vt (transposed bf16).
// -------------------------------------------------------------------------
__global__ __launch_bounds__(256) void qkv_proj(
    const bf16_t* __restrict__ ybf, const bf16_t* __restrict__ xbf,
    const bf16_t* __restrict__ wqt, const bf16_t* __restrict__ wkt,
    const bf16_t* __restrict__ wvt,
    const float* __restrict__ bq, const float* __restrict__ bk,
    const float* __restrict__ bv,
    bf16_t* __restrict__ Qt, bf16_t* __restrict__ Kb, bf16_t* __restrict__ Vt)
{
    const int z = blockIdx.z;
    const bf16_t* A  = (z == 1) ? xbf : ybf;
    const bf16_t* Bt = (z == 0) ? wqt : (z == 1) ? wkt : wvt;
    const float* bias = (z == 0) ? bq : (z == 1) ? bk : bv;
    const int K = C_;

    __shared__ bf16_t As[128 * 32];
    __shared__ bf16_t Bs[128 * 32];

    const int t = threadIdx.x;
    const int w = t >> 6, lane = t & 63;
    const int wm = (w >> 1) * 64, wn = (w & 1) * 64;
    const int l15 = lane & 15, l4 = lane >> 4;
    const int row0 = blockIdx.y * 128, col0 = blockIdx.x * 128;

    const int sr = t >> 2, sk = (t & 3) * 8;
    const bf16_t* gA = A + (size_t)(row0 + sr) * K + sk;
    const bf16_t* gB = Bt + (size_t)(col0 + sr) * K + sk;
    bf16_t* lA = As + (t & ~63) * 8;
    bf16_t* lB = Bs + (t & ~63) * 8;

    f32x4 acc[4][4] = {};

    for (int k0 = 0; k0 < K; k0 += 32) {
        __syncthreads();
        gload16(gA + k0, lA);
        gload16(gA + k0 + (size_t)64 * K, lA + 2048);
        gload16(gB + k0, lB);
        gload16(gB + k0 + (size_t)64 * K, lB + 2048);
        __syncthreads();
        bf16x8 a[4], b[4];
        #pragma unroll
        for (int i = 0; i < 4; ++i)
            a[i] = *(const bf16x8*)&As[(wm + i * 16 + l15) * 32 + l4 * 8];
        #pragma unroll
        for (int j = 0; j < 4; ++j)
            b[j] = *(const bf16x8*)&Bs[(wn + j * 16 + l15) * 32 + l4 * 8];
        #pragma unroll
        for (int i = 0; i < 4; ++i)
            #pragma unroll
            for (int j = 0; j < 4; ++j)
                acc[i][j] = __builtin_amdgcn_mfma_f32_16x16x32_bf16(
                    a[i], b[j], acc[i][j], 0, 0, 0);
    }

    if (z != 1) {
        bf16_t* To = (z == 0) ? Qt : Vt;
        #pragma unroll
        for (int i = 0; i < 4; ++i) {
            int mb = row0 + wm + i * 16 + l4 * 4;
            int b2 = mb >> 11, s = mb & 2047;
            #pragma unroll
            for (int j = 0; j < 4; ++j) {
                int c = col0 + wn + j * 16 + l15;
                float bv2 = bias[c];
                bf16x4 o;
                #pragma unroll
                for (int r = 0; r < 4; ++r) o[r] = (bf16_t)(acc[i][j][r] + bv2);
                *(bf16x4*)&To[((size_t)b2 * C_ + c) * S_ + s] = o;
            }
        }
    } else {
        #pragma unroll
        for (int i = 0; i < 4; ++i)
            #pragma unroll
            for (int j = 0; j < 4; ++j) {
                int c = col0 + wn + j * 16 + l15;
                float bv2 = bias[c];
                #pragma unroll
                for (int r = 0; r < 4; ++r) {
                    int m = row0 + wm + i * 16 + l4 * 4 + r;
                    Kb[(size_t)m * C_ + c] = (bf16_t)(acc[i][j][r] + bv2);
                }
            }
    }
}

// -------------------------------------------------------------------------
// FUSED cv + qtcv:
//   cv(q,d) = sum_{s in p-range} tanh(t*wc+bc) * V[s,d]    (MFMA, 128qx64d)
//   then M[bh,d',d] += sum_q Qt[d',q] * cv(q,d)            (MFMA, atomics)
// grid (S/128=16, P=4, BH=32) = 2048 blocks, 8 blocks/CU.
// LDS: main loop As(8K)+Bs(4K); epilogue cvs 4x64x40 bf16 (20K), aliased.
// -------------------------------------------------------------------------
__global__ __launch_bounds__(256) void cv_qtcv_fused(
    const float* __restrict__ t_mat, const bf16_t* __restrict__ Vt,
    const bf16_t* __restrict__ Qt,
    const float* __restrict__ wc, const float* __restrict__ bc,
    float* __restrict__ Mm)
{
    const int bh = blockIdx.z, b = bh >> 4, h = bh & 15;
    const int q0 = blockIdx.x * 128;
    const int p = blockIdx.y;
    const int t = threadIdx.x;
    const int w = t >> 6, lane = t & 63;
    const int l15 = lane & 15, l4 = lane >> 4;

    __shared__ bf16_t smem[10240];       // 20 KB
    bf16_t* As = smem;                   // 128*32
    bf16_t* Bs = smem + 4096;            // 64*32
    bf16_t* cvs = smem;                  // epilogue: [c][64][40]

    const float LOG2E2 = 2.8853900817779268f;  // 2/ln2
    const float wch2 = wc[h] * LOG2E2, bch2 = bc[h] * LOG2E2;
    const float* tb = t_mat + (size_t)b * S_ * S_ + (size_t)q0 * S_;
    const bf16_t* Vb = Vt + ((size_t)b * C_ + h * 64) * S_;

    const int rr = t >> 1, sp = (t & 1) * 16;   // A staging: row, s-offset
    const int vd = t >> 2, vse = (t & 3) * 8;   // B staging
    bf16_t* lB = Bs + (t & ~63) * 8;

    f32x4 acc[2][4] = {};

    const int s_beg = p * 512, s_end = s_beg + 512;
    for (int s0 = s_beg; s0 < s_end; s0 += 32) {
        const float* trow = tb + (size_t)rr * S_ + s0 + sp;
        float4 v0 = *(const float4*)&trow[0];
        float4 v1 = *(const float4*)&trow[4];
        float4 v2 = *(const float4*)&trow[8];
        float4 v3 = *(const float4*)&trow[12];
        bf16x8 p0, p1;
        p0[0] = (bf16_t)tanh_folded(v0.x, wch2, bch2);
        p0[1] = (bf16_t)tanh_folded(v0.y, wch2, bch2);
        p0[2] = (bf16_t)tanh_folded(v0.z, wch2, bch2);
        p0[3] = (bf16_t)tanh_folded(v0.w, wch2, bch2);
        p0[4] = (bf16_t)tanh_folded(v1.x, wch2, bch2);
        p0[5] = (bf16_t)tanh_folded(v1.y, wch2, bch2);
        p0[6] = (bf16_t)tanh_folded(v1.z, wch2, bch2);
        p0[7] = (bf16_t)tanh_folded(v1.w, wch2, bch2);
        p1[0] = (bf16_t)tanh_folded(v2.x, wch2, bch2);
        p1[1] = (bf16_t)tanh_folded(v2.y, wch2, bch2);
        p1[2] = (bf16_t)tanh_folded(v2.z, wch2, bch2);
        p1[3] = (bf16_t)tanh_folded(v2.w, wch2, bch2);
        p1[4] = (bf16_t)tanh_folded(v3.x, wch2, bch2);
        p1[5] = (bf16_t)tanh_folded(v3.y, wch2, bch2);
        p1[6] = (bf16_t)tanh_folded(v3.z, wch2, bch2);
        p1[7] = (bf16_t)tanh_folded(v3.w, wch2, bch2);
        __syncthreads();
        gload16(Vb + (size_t)vd * S_ + s0 + vse, lB);
        *(bf16x8*)&As[rr * 32 + sp] = p0;
        *(bf16x8*)&As[rr * 32 + sp + 8] = p1;
        __syncthreads();
        bf16x8 a0 = *(const bf16x8*)&As[(w * 32 + l15) * 32 + l4 * 8];
        bf16x8 a1 = *(const bf16x8*)&As[(w * 32 + 16 + l15) * 32 + l4 * 8];
        #pragma unroll
        for (int j = 0; j < 4; ++j) {
            bf16x8 bb = *(const bf16x8*)&Bs[(j * 16 + l15) * 32 + l4 * 8];
            acc[0][j] = __builtin_amdgcn_mfma_f32_16x16x32_bf16(a0, bb, acc[0][j], 0, 0, 0);
            acc[1][j] = __builtin_amdgcn_mfma_f32_16x16x32_bf16(a1, bb, acc[1][j], 0, 0, 0);
        }
    }

    // ---- epilogue: M[d',d] += Qt[d',q] * cv(q,d) over this block's q-tile
    __syncthreads();   // all MFMA LDS reads done; safe to overwrite as cvs
    // write cv acc (C-layout) to cvs[c=w][d][qin], qin = i*16+l4*4, pad 40
    #pragma unroll
    for (int i = 0; i < 2; ++i)
        #pragma unroll
        for (int j = 0; j < 4; ++j) {
            int d = j * 16 + l15;
            bf16x4 o;
            #pragma unroll
            for (int r = 0; r < 4; ++r) o[r] = (bf16_t)acc[i][j][r];
            *(bf16x4*)&cvs[(size_t)w * 2560 + d * 40 + i * 16 + l4 * 4] = o;
        }
    __syncthreads();

    // A-operand: Qt rows d' = h*64 + w*16 + l15, k = q0 + c*32 + l4*8 (global)
    const bf16_t* Qrow = Qt + ((size_t)b * C_ + h * 64 + w * 16 + l15) * S_ + q0 + l4 * 8;
    f32x4 macc[4] = {};
    #pragma unroll
    for (int c = 0; c < 4; ++c) {
        bf16x8 a = *(const bf16x8*)&Qrow[c * 32];
        #pragma unroll
        for (int j = 0; j < 4; ++j) {
            bf16x8 bb = *(const bf16x8*)&cvs[(size_t)c * 2560 + (j * 16 + l15) * 40 + l4 * 8];
            macc[j] = __builtin_amdgcn_mfma_f32_16x16x32_bf16(a, bb, macc[j], 0, 0, 0);
        }
    }

    float* mp = Mm + (size_t)bh * 64 * 64;
    #pragma unroll
    for (int j = 0; j < 4; ++j)
        #pragma unroll
        for (int r = 0; r < 4; ++r)
            atomicAdd(&mp[(size_t)(w * 16 + l4 * 4 + r) * 64 + j * 16 + l15],
                      macc[j][r]);
}

// -------------------------------------------------------------------------
// Wefft[b, co, h*64+d'] = (1/8) * sum_d M[bh,d',d] * wf[h*64+d, co]  (bf16)
// -------------------------------------------------------------------------
__global__ __launch_bounds__(256) void weff_kernel(
    const float* __restrict__ Mm, const float* __restrict__ wf,
    bf16_t* __restrict__ Wefft)
{
    const int b = blockIdx.z, h = blockIdx.y;
    const int co0 = blockIdx.x * 64;
    const int t = threadIdx.x;
    const int tx = t & 15, ty = t >> 4;

    __shared__ float Ms[64][64];
    __shared__ float Ws[64][64];

    const float* Mb = Mm + (size_t)(b * H_ + h) * 64 * 64;

    const int r  = t >> 2;
    const int c4 = (t & 3) << 2;

    #pragma unroll
    for (int rep = 0; rep < 4; ++rep) {
        int col = c4 + rep * 16;
        float4 m4 = *(const float4*)&Mb[(size_t)r * 64 + col];
        Ms[col + 0][r] = m4.x; Ms[col + 1][r] = m4.y;
        Ms[col + 2][r] = m4.z; Ms[col + 3][r] = m4.w;
        float4 w4 = *(const float4*)&wf[(size_t)(h * 64 + r) * C_ + co0 + col];
        *(float4*)&Ws[r][col] = w4;
    }
    __syncthreads();

    float acc[4][4] = {};
    #pragma unroll
    for (int kk = 0; kk < 64; ++kk) {
        float av[4], bv2[4];
        *(float4*)&av[0] = *(const float4*)&Ms[kk][ty * 4];
        *(float4*)&bv2[0] = *(const float4*)&Ws[kk][tx * 4];
        #pragma unroll
        for (int i = 0; i < 4; ++i)
            #pragma unroll
            for (int j = 0; j < 4; ++j)
                acc[i][j] = fmaf(av[i], bv2[j], acc[i][j]);
    }

    bf16_t* wp = Wefft + (size_t)b * C_ * C_;
    #pragma unroll
    for (int i = 0; i < 4; ++i)
        #pragma unroll
        for (int j = 0; j < 4; ++j)
            wp[(size_t)(co0 + tx * 4 + j) * C_ + h * 64 + ty * 4 + i] =
                (bf16_t)(acc[i][j] * 0.125f);  // fold 1/sqrt(D)=1/8
}

// -------------------------------------------------------------------------
// out = mish(Kb[b] @ Wefft[b]^T + bf), fp32 out. 128x64 tiles,
// grid (16, 16, 2) = 512 blocks (2/CU).
// -------------------------------------------------------------------------
__global__ __launch_bounds__(256) void final_gemm(
    const bf16_t* __restrict__ Kb, const bf16_t* __restrict__ Weft,
    const float* __restrict__ bias, float* __restrict__ out)
{
    const int z = blockIdx.z;
    const bf16_t* A  = Kb + (size_t)z * S_ * C_;
    const bf16_t* Bt = Weft + (size_t)z * C_ * C_;
    float* Co = out + (size_t)z * S_ * C_;
    const int K = C_;

    __shared__ bf16_t As[128 * 32];
    __shared__ bf16_t Bs[64 * 32];

    const int t = threadIdx.x;
    const int w = t >> 6, lane = t & 63;
    const int l15 = lane & 15, l4 = lane >> 4;
    const int row0 = blockIdx.y * 128, col0 = blockIdx.x * 64;

    const int sr = t >> 2, sk = (t & 3) * 8;
    const bf16_t* gA = A + (size_t)(row0 + sr) * K + sk;
    const bf16_t* gB = Bt + (size_t)(col0 + sr) * K + sk;
    bf16_t* lA = As + (t & ~63) * 8;
    bf16_t* lB = Bs + (t & ~63) * 8;

    f32x4 acc[2][4] = {};

    for (int k0 = 0; k0 < K; k0 += 32) {
        __syncthreads();
        gload16(gA + k0, lA);
        gload16(gA + k0 + (size_t)64 * K, lA + 2048);
        gload16(gB + k0, lB);
        __syncthreads();
        bf16x8 a0 = *(const bf16x8*)&As[(w * 32 + l15) * 32 + l4 * 8];
        bf16x8 a1 = *(const bf16x8*)&As[(w * 32 + 16 + l15) * 32 + l4 * 8];
        #pragma unroll
        for (int j = 0; j < 4; ++j) {
            bf16x8 bb = *(const bf16x8*)&Bs[(j * 16 + l15) * 32 + l4 * 8];
            acc[0][j] = __builtin_amdgcn_mfma_f32_16x16x32_bf16(a0, bb, acc[0][j], 0, 0, 0);
            acc[1][j] = __builtin_amdgcn_mfma_f32_16x16x32_bf16(a1, bb, acc[1][j], 0, 0, 0);
        }
    }

    #pragma unroll
    for (int i = 0; i < 2; ++i)
        #pragma unroll
        for (int j = 0; j < 4; ++j) {
            int c = col0 + j * 16 + l15;
            float bv2 = bias[c];
            #pragma unroll
            for (int r = 0; r < 4; ++r) {
                int m = row0 + w * 32 + i * 16 + l4 * 4 + r;
                Co[(size_t)m * C_ + c] = mish_f(acc[i][j][r] + bv2);
            }
        }
}

// -------------------------------------------------------------------------
extern "C" void kernel_launch(void* const* d_in, const int* in_sizes, int n_in,
                              void* d_out, int out_size, void* d_ws, size_t ws_size,
                              hipStream_t stream) {
    const float* x     = (const float*)d_in[0];
    const float* y     = (const float*)d_in[1];
    const float* t_mat = (const float*)d_in[2];
    const float* wq    = (const float*)d_in[3];
    const float* bq    = (const float*)d_in[4];
    const float* wk    = (const float*)d_in[5];
    const float* bk    = (const float*)d_in[6];
    const float* wv    = (const float*)d_in[7];
    const float* bv    = (const float*)d_in[8];
    const float* wc    = (const float*)d_in[9];
    const float* bc    = (const float*)d_in[10];
    const float* wf    = (const float*)d_in[11];
    const float* bf    = (const float*)d_in[12];
    float* out = (float*)d_out;

    // workspace layout (byte offsets)
    char* base = (char*)d_ws;
    bf16_t* Qt   = (bf16_t*)(base + 0);          //  8 MiB  [b][c][s]
    bf16_t* Kb   = (bf16_t*)(base + 8388608);    //  8 MiB  [b*s][c]
    bf16_t* Vt   = (bf16_t*)(base + 16777216);   //  8 MiB  [b][c][s]
    float*  Mm   = (float*) (base + 25165824);   //  0.5 MiB
    bf16_t* Weft = (bf16_t*)(base + 25690112);   //  4 MiB  [b][co][cin]
    bf16_t* ybf  = (bf16_t*)(base + 29884416);   //  8 MiB
    bf16_t* xbf  = (bf16_t*)(base + 38273024);   //  8 MiB
    bf16_t* wqt  = (bf16_t*)(base + 46661632);   //  2 MiB
    bf16_t* wkt  = (bf16_t*)(base + 48758784);   //  2 MiB
    bf16_t* wvt  = (bf16_t*)(base + 50855936);   //  2 MiB

    hipMemsetAsync(Mm, 0, (size_t)B_ * H_ * 64 * 64 * sizeof(float), stream);

    dim3 blk(256);

    cvt2_bf16<<<dim3((B_ * S_ * C_) / (256 * 8), 2), blk, 0, stream>>>(
        y, ybf, x, xbf);
    wtrans_bf16<<<dim3(16, 16, 3), blk, 0, stream>>>(wq, wk, wv, wqt, wkt, wvt);

    // fused QKV projections (768 blocks)
    qkv_proj<<<dim3(C_ / 128, (B_ * S_) / 128, 3), blk, 0, stream>>>(
        ybf, xbf, wqt, wkt, wvt, bq, bk, bv, Qt, Kb, Vt);

    // fused cv + M-accumulation (2048 blocks)
    cv_qtcv_fused<<<dim3(S_ / 128, 4, B_ * H_), blk, 0, stream>>>(
        t_mat, Vt, Qt, wc, bc, Mm);

    // Weff^T (bf16), 1/8 folded
    weff_kernel<<<dim3(C_ / 64, H_, B_), blk, 0, stream>>>(Mm, wf, Weft);

    // out = mish(K @ Weff + bf), 512 blocks
    final_gemm<<<dim3(C_ / 64, S_ / 128, B_), blk, 0, stream>>>(
        Kb, Weft, bf, out);
}

// Round 5
// 274.059 us; speedup vs baseline: 3.6063x; 1.0118x over previous
//
#include <hip/hip_runtime.h>
#include <math.h>

#define B_ 2
#define S_ 2048
#define C_ 1024
#define H_ 16
#define D_ 64

typedef __bf16 bf16_t;
typedef __attribute__((ext_vector_type(8))) __bf16 bf16x8;
typedef __attribute__((ext_vector_type(4))) __bf16 bf16x4;
typedef __attribute__((ext_vector_type(4))) float f32x4;

__device__ __forceinline__ void gload16(const void* g, void* l) {
    __builtin_amdgcn_global_load_lds(
        (const __attribute__((address_space(1))) unsigned int*)g,
        (__attribute__((address_space(3))) unsigned int*)l, 16, 0, 0);
}

__device__ __forceinline__ float tanh_fast(float z) {
    z = fminf(fmaxf(z, -12.f), 12.f);
    float e = __expf(2.f * z);
    return 1.f - __fdividef(2.f, e + 1.f);
}

__device__ __forceinline__ float mish_f(float x) {
    float sp = (x > 15.f) ? x : log1pf(__expf(x));
    return x * tanh_fast(sp);
}

// tanh(t*w+b) with 2/ln2 pre-folded into w2,b2: 1 - 2*rcp(exp2(t*w2+b2)+1)
__device__ __forceinline__ float tanh_folded(float t, float w2, float b2) {
    float e = __builtin_amdgcn_exp2f(fmaf(t, w2, b2));
    float r = __builtin_amdgcn_rcpf(e + 1.f);
    return fmaf(-2.f, r, 1.f);
}

// -------------------------------------------------------------------------
// Merged preprocessing: blocks 0..4095 = fp32->bf16 of y,x;
// blocks 4096..4863 = transpose-convert wq/wk/wv -> [N][K] bf16.
// -------------------------------------------------------------------------
__global__ __launch_bounds__(256) void prep_kernel(
    const float* __restrict__ y, bf16_t* __restrict__ ybf,
    const float* __restrict__ x, bf16_t* __restrict__ xbf,
    const float* __restrict__ wq, const float* __restrict__ wk,
    const float* __restrict__ wv,
    bf16_t* __restrict__ wqt, bf16_t* __restrict__ wkt,
    bf16_t* __restrict__ wvt)
{
    __shared__ float ts[64][65];
    const int bid = blockIdx.x;
    const int t = threadIdx.x;
    if (bid < 4096) {
        const float* in = (bid < 2048) ? y : x;
        bf16_t* out = (bid < 2048) ? ybf : xbf;
        size_t i = ((size_t)(bid & 2047) * 256 + t) * 8;
        float4 u = *(const float4*)&in[i];
        float4 v = *(const float4*)&in[i + 4];
        bf16x8 o;
        o[0] = (bf16_t)u.x; o[1] = (bf16_t)u.y; o[2] = (bf16_t)u.z; o[3] = (bf16_t)u.w;
        o[4] = (bf16_t)v.x; o[5] = (bf16_t)v.y; o[6] = (bf16_t)v.z; o[7] = (bf16_t)v.w;
        *(bf16x8*)&out[i] = o;
    } else {
        const int r3 = bid - 4096;           // 0..767
        const int z = r3 >> 8;
        const int rem = r3 & 255;
        const int k0 = (rem >> 4) * 64, n0 = (rem & 15) * 64;
        const float* in = z == 0 ? wq : (z == 1 ? wk : wv);
        bf16_t* out = z == 0 ? wqt : (z == 1 ? wkt : wvt);
        const int r = t >> 2, c0 = (t & 3) * 16;
        #pragma unroll
        for (int j = 0; j < 16; j += 4) {
            float4 v = *(const float4*)&in[(size_t)(k0 + r) * C_ + n0 + c0 + j];
            ts[c0 + j + 0][r] = v.x; ts[c0 + j + 1][r] = v.y;
            ts[c0 + j + 2][r] = v.z; ts[c0 + j + 3][r] = v.w;
        }
        __syncthreads();
        #pragma unroll
        for (int g = 0; g < 2; ++g) {
            bf16x8 o;
            #pragma unroll
            for (int e = 0; e < 8; ++e) o[e] = (bf16_t)ts[r][c0 + g * 8 + e];
            *(bf16x8*)&out[(size_t)(n0 + r) * C_ + k0 + c0 + g * 8] = o;
        }
    }
}

// -------------------------------------------------------------------------
// Fused QKV projection, one launch. z=0: y@wq -> Qt (transposed bf16),
// z=1: x@wk -> Kb (row-major bf16), z=2: y@wv -> Vt (transposed bf16).
// -------------------------------------------------------------------------
__global__ __launch_bounds__(256) void qkv_proj(
    const bf16_t* __restrict__ ybf, const bf16_t* __restrict__ xbf,
    const bf16_t* __restrict__ wqt, const bf16_t* __restrict__ wkt,
    const bf16_t* __restrict__ wvt,
    const float* __restrict__ bq, const float* __restrict__ bk,
    const float* __restrict__ bv,
    bf16_t* __restrict__ Qt, bf16_t* __restrict__ Kb, bf16_t* __restrict__ Vt)
{
    const int z = blockIdx.z;
    const bf16_t* A  = (z == 1) ? xbf : ybf;
    const bf16_t* Bt = (z == 0) ? wqt : (z == 1) ? wkt : wvt;
    const float* bias = (z == 0) ? bq : (z == 1) ? bk : bv;
    const int K = C_;

    __shared__ bf16_t As[128 * 32];
    __shared__ bf16_t Bs[128 * 32];

    const int t = threadIdx.x;
    const int w = t >> 6, lane = t & 63;
    const int wm = (w >> 1) * 64, wn = (w & 1) * 64;
    const int l15 = lane & 15, l4 = lane >> 4;
    const int row0 = blockIdx.y * 128, col0 = blockIdx.x * 128;

    const int sr = t >> 2, sk = (t & 3) * 8;
    const bf16_t* gA = A + (size_t)(row0 + sr) * K + sk;
    const bf16_t* gB = Bt + (size_t)(col0 + sr) * K + sk;
    bf16_t* lA = As + (t & ~63) * 8;
    bf16_t* lB = Bs + (t & ~63) * 8;

    f32x4 acc[4][4] = {};

    for (int k0 = 0; k0 < K; k0 += 32) {
        __syncthreads();
        gload16(gA + k0, lA);
        gload16(gA + k0 + (size_t)64 * K, lA + 2048);
        gload16(gB + k0, lB);
        gload16(gB + k0 + (size_t)64 * K, lB + 2048);
        __syncthreads();
        bf16x8 a[4], b[4];
        #pragma unroll
        for (int i = 0; i < 4; ++i)
            a[i] = *(const bf16x8*)&As[(wm + i * 16 + l15) * 32 + l4 * 8];
        #pragma unroll
        for (int j = 0; j < 4; ++j)
            b[j] = *(const bf16x8*)&Bs[(wn + j * 16 + l15) * 32 + l4 * 8];
        #pragma unroll
        for (int i = 0; i < 4; ++i)
            #pragma unroll
            for (int j = 0; j < 4; ++j)
                acc[i][j] = __builtin_amdgcn_mfma_f32_16x16x32_bf16(
                    a[i], b[j], acc[i][j], 0, 0, 0);
    }

    if (z != 1) {
        bf16_t* To = (z == 0) ? Qt : Vt;
        #pragma unroll
        for (int i = 0; i < 4; ++i) {
            int mb = row0 + wm + i * 16 + l4 * 4;
            int b2 = mb >> 11, s = mb & 2047;
            #pragma unroll
            for (int j = 0; j < 4; ++j) {
                int c = col0 + wn + j * 16 + l15;
                float bv2 = bias[c];
                bf16x4 o;
                #pragma unroll
                for (int r = 0; r < 4; ++r) o[r] = (bf16_t)(acc[i][j][r] + bv2);
                *(bf16x4*)&To[((size_t)b2 * C_ + c) * S_ + s] = o;
            }
        }
    } else {
        #pragma unroll
        for (int i = 0; i < 4; ++i)
            #pragma unroll
            for (int j = 0; j < 4; ++j) {
                int c = col0 + wn + j * 16 + l15;
                float bv2 = bias[c];
                #pragma unroll
                for (int r = 0; r < 4; ++r) {
                    int m = row0 + wm + i * 16 + l4 * 4 + r;
                    Kb[(size_t)m * C_ + c] = (bf16_t)(acc[i][j][r] + bv2);
                }
            }
    }
}

// -------------------------------------------------------------------------
// FUSED cv + qtcv, single-barrier K-loop:
//   As (tanh tiles) is WAVE-PRIVATE: wave w computes exactly the q-rows
//   (w*32..w*32+31) it MFMA-reads -> no barrier needed for As (same-wave
//   DS ops are in-order). Bs (Vt staging) is cross-wave -> double-buffered,
//   ONE __syncthreads per iter (its vmcnt drain also covers gload16).
//   t_mat float4s for iter i+1 are register-prefetched after the barrier.
// grid (S/128=16, P=4, BH=32) = 2048 blocks, 8 blocks/CU (20 KB LDS).
// -------------------------------------------------------------------------
__global__ __launch_bounds__(256) void cv_qtcv_fused(
    const float* __restrict__ t_mat, const bf16_t* __restrict__ Vt,
    const bf16_t* __restrict__ Qt,
    const float* __restrict__ wc, const float* __restrict__ bc,
    float* __restrict__ Mm)
{
    const int bh = blockIdx.z, b = bh >> 4, h = bh & 15;
    const int q0 = blockIdx.x * 128;
    const int p = blockIdx.y;
    const int t = threadIdx.x;
    const int w = t >> 6, lane = t & 63;
    const int l15 = lane & 15, l4 = lane >> 4;

    __shared__ bf16_t smem[10240];       // 20 KB
    bf16_t* As = smem;                   // 128*32 = 4096 bf16 (8 KB)
    bf16_t* Bs = smem + 4096;            // 2 bufs x 64*32 = 2x2048 bf16 (8 KB)
    bf16_t* cvs = smem;                  // epilogue: [c][64][40] (20 KB)

    const float LOG2E2 = 2.8853900817779268f;  // 2/ln2
    const float wch2 = wc[h] * LOG2E2, bch2 = bc[h] * LOG2E2;
    const float* tb = t_mat + (size_t)b * S_ * S_ + (size_t)q0 * S_;
    const bf16_t* Vb = Vt + ((size_t)b * C_ + h * 64) * S_;

    const int rr = t >> 1, sp = (t & 1) * 16;   // A: row (wave-aligned), s-off
    const int vd = t >> 2, vse = (t & 3) * 8;   // B staging
    const int lBoff = (t & ~63) * 8;            // per-wave Bs slice

    f32x4 acc[2][4] = {};

    const int s_beg = p * 512, s_end = s_beg + 512;
    const float* trow = tb + (size_t)rr * S_ + sp;

    // prime the t_mat prefetch registers
    float4 v0 = *(const float4*)&trow[s_beg];
    float4 v1 = *(const float4*)&trow[s_beg + 4];
    float4 v2 = *(const float4*)&trow[s_beg + 8];
    float4 v3 = *(const float4*)&trow[s_beg + 12];

    int buf = 0;
    for (int s0 = s_beg; s0 < s_end; s0 += 32, buf ^= 1) {
        bf16x8 p0, p1;
        p0[0] = (bf16_t)tanh_folded(v0.x, wch2, bch2);
        p0[1] = (bf16_t)tanh_folded(v0.y, wch2, bch2);
        p0[2] = (bf16_t)tanh_folded(v0.z, wch2, bch2);
        p0[3] = (bf16_t)tanh_folded(v0.w, wch2, bch2);
        p0[4] = (bf16_t)tanh_folded(v1.x, wch2, bch2);
        p0[5] = (bf16_t)tanh_folded(v1.y, wch2, bch2);
        p0[6] = (bf16_t)tanh_folded(v1.z, wch2, bch2);
        p0[7] = (bf16_t)tanh_folded(v1.w, wch2, bch2);
        p1[0] = (bf16_t)tanh_folded(v2.x, wch2, bch2);
        p1[1] = (bf16_t)tanh_folded(v2.y, wch2, bch2);
        p1[2] = (bf16_t)tanh_folded(v2.z, wch2, bch2);
        p1[3] = (bf16_t)tanh_folded(v2.w, wch2, bch2);
        p1[4] = (bf16_t)tanh_folded(v3.x, wch2, bch2);
        p1[5] = (bf16_t)tanh_folded(v3.y, wch2, bch2);
        p1[6] = (bf16_t)tanh_folded(v3.z, wch2, bch2);
        p1[7] = (bf16_t)tanh_folded(v3.w, wch2, bch2);
        // stage Vt chunk into this iter's Bs buffer (async DMA)
        gload16(Vb + (size_t)vd * S_ + s0 + vse, Bs + buf * 2048 + lBoff);
        // wave-private As write (no cross-wave hazard)
        *(bf16x8*)&As[rr * 32 + sp] = p0;
        *(bf16x8*)&As[rr * 32 + sp + 8] = p1;
        __syncthreads();   // drains vmcnt (gload) + lgkmcnt for all waves
        // prefetch next iter's t_mat into regs (consumed after next barrier)
        if (s0 + 32 < s_end) {
            const float* nrow = &trow[s0 + 32];
            v0 = *(const float4*)&nrow[0];
            v1 = *(const float4*)&nrow[4];
            v2 = *(const float4*)&nrow[8];
            v3 = *(const float4*)&nrow[12];
        }
        bf16x8 a0 = *(const bf16x8*)&As[(w * 32 + l15) * 32 + l4 * 8];
        bf16x8 a1 = *(const bf16x8*)&As[(w * 32 + 16 + l15) * 32 + l4 * 8];
        #pragma unroll
        for (int j = 0; j < 4; ++j) {
            bf16x8 bb = *(const bf16x8*)&Bs[buf * 2048 + (j * 16 + l15) * 32 + l4 * 8];
            acc[0][j] = __builtin_amdgcn_mfma_f32_16x16x32_bf16(a0, bb, acc[0][j], 0, 0, 0);
            acc[1][j] = __builtin_amdgcn_mfma_f32_16x16x32_bf16(a1, bb, acc[1][j], 0, 0, 0);
        }
    }

    // ---- epilogue: M[d',d] += Qt[d',q] * cv(q,d) over this block's q-tile
    __syncthreads();   // all waves done with As/Bs; safe to overwrite as cvs
    #pragma unroll
    for (int i = 0; i < 2; ++i)
        #pragma unroll
        for (int j = 0; j < 4; ++j) {
            int d = j * 16 + l15;
            bf16x4 o;
            #pragma unroll
            for (int r = 0; r < 4; ++r) o[r] = (bf16_t)acc[i][j][r];
            *(bf16x4*)&cvs[(size_t)w * 2560 + d * 40 + i * 16 + l4 * 4] = o;
        }
    __syncthreads();

    // A-operand: Qt rows d' = h*64 + w*16 + l15, k = q0 + c*32 + l4*8 (global)
    const bf16_t* Qrow = Qt + ((size_t)b * C_ + h * 64 + w * 16 + l15) * S_ + q0 + l4 * 8;
    f32x4 macc[4] = {};
    #pragma unroll
    for (int c = 0; c < 4; ++c) {
        bf16x8 a = *(const bf16x8*)&Qrow[c * 32];
        #pragma unroll
        for (int j = 0; j < 4; ++j) {
            bf16x8 bb = *(const bf16x8*)&cvs[(size_t)c * 2560 + (j * 16 + l15) * 40 + l4 * 8];
            macc[j] = __builtin_amdgcn_mfma_f32_16x16x32_bf16(a, bb, macc[j], 0, 0, 0);
        }
    }

    float* mp = Mm + (size_t)bh * 64 * 64;
    #pragma unroll
    for (int j = 0; j < 4; ++j)
        #pragma unroll
        for (int r = 0; r < 4; ++r)
            atomicAdd(&mp[(size_t)(w * 16 + l4 * 4 + r) * 64 + j * 16 + l15],
                      macc[j][r]);
}

// -------------------------------------------------------------------------
// Wefft[b, co, h*64+d'] = (1/8) * sum_d M[bh,d',d] * wf[h*64+d, co]  (bf16)
// -------------------------------------------------------------------------
__global__ __launch_bounds__(256) void weff_kernel(
    const float* __restrict__ Mm, const float* __restrict__ wf,
    bf16_t* __restrict__ Wefft)
{
    const int b = blockIdx.z, h = blockIdx.y;
    const int co0 = blockIdx.x * 64;
    const int t = threadIdx.x;
    const int tx = t & 15, ty = t >> 4;

    __shared__ float Ms[64][64];
    __shared__ float Ws[64][64];

    const float* Mb = Mm + (size_t)(b * H_ + h) * 64 * 64;

    const int r  = t >> 2;
    const int c4 = (t & 3) << 2;

    #pragma unroll
    for (int rep = 0; rep < 4; ++rep) {
        int col = c4 + rep * 16;
        float4 m4 = *(const float4*)&Mb[(size_t)r * 64 + col];
        Ms[col + 0][r] = m4.x; Ms[col + 1][r] = m4.y;
        Ms[col + 2][r] = m4.z; Ms[col + 3][r] = m4.w;
        float4 w4 = *(const float4*)&wf[(size_t)(h * 64 + r) * C_ + co0 + col];
        *(float4*)&Ws[r][col] = w4;
    }
    __syncthreads();

    float acc[4][4] = {};
    #pragma unroll
    for (int kk = 0; kk < 64; ++kk) {
        float av[4], bv2[4];
        *(float4*)&av[0] = *(const float4*)&Ms[kk][ty * 4];
        *(float4*)&bv2[0] = *(const float4*)&Ws[kk][tx * 4];
        #pragma unroll
        for (int i = 0; i < 4; ++i)
            #pragma unroll
            for (int j = 0; j < 4; ++j)
                acc[i][j] = fmaf(av[i], bv2[j], acc[i][j]);
    }

    bf16_t* wp = Wefft + (size_t)b * C_ * C_;
    #pragma unroll
    for (int i = 0; i < 4; ++i)
        #pragma unroll
        for (int j = 0; j < 4; ++j)
            wp[(size_t)(co0 + tx * 4 + j) * C_ + h * 64 + ty * 4 + i] =
                (bf16_t)(acc[i][j] * 0.125f);  // fold 1/sqrt(D)=1/8
}

// -------------------------------------------------------------------------
// out = mish(Kb[b] @ Wefft[b]^T + bf), fp32 out. 128x64 tiles,
// grid (16, 16, 2) = 512 blocks (2/CU).
// -------------------------------------------------------------------------
__global__ __launch_bounds__(256) void final_gemm(
    const bf16_t* __restrict__ Kb, const bf16_t* __restrict__ Weft,
    const float* __restrict__ bias, float* __restrict__ out)
{
    const int z = blockIdx.z;
    const bf16_t* A  = Kb + (size_t)z * S_ * C_;
    const bf16_t* Bt = Weft + (size_t)z * C_ * C_;
    float* Co = out + (size_t)z * S_ * C_;
    const int K = C_;

    __shared__ bf16_t As[128 * 32];
    __shared__ bf16_t Bs[64 * 32];

    const int t = threadIdx.x;
    const int w = t >> 6, lane = t & 63;
    const int l15 = lane & 15, l4 = lane >> 4;
    const int row0 = blockIdx.y * 128, col0 = blockIdx.x * 64;

    const int sr = t >> 2, sk = (t & 3) * 8;
    const bf16_t* gA = A + (size_t)(row0 + sr) * K + sk;
    const bf16_t* gB = Bt + (size_t)(col0 + sr) * K + sk;
    bf16_t* lA = As + (t & ~63) * 8;
    bf16_t* lB = Bs + (t & ~63) * 8;

    f32x4 acc[2][4] = {};

    for (int k0 = 0; k0 < K; k0 += 32) {
        __syncthreads();
        gload16(gA + k0, lA);
        gload16(gA + k0 + (size_t)64 * K, lA + 2048);
        gload16(gB + k0, lB);
        __syncthreads();
        bf16x8 a0 = *(const bf16x8*)&As[(w * 32 + l15) * 32 + l4 * 8];
        bf16x8 a1 = *(const bf16x8*)&As[(w * 32 + 16 + l15) * 32 + l4 * 8];
        #pragma unroll
        for (int j = 0; j < 4; ++j) {
            bf16x8 bb = *(const bf16x8*)&Bs[(j * 16 + l15) * 32 + l4 * 8];
            acc[0][j] = __builtin_amdgcn_mfma_f32_16x16x32_bf16(a0, bb, acc[0][j], 0, 0, 0);
            acc[1][j] = __builtin_amdgcn_mfma_f32_16x16x32_bf16(a1, bb, acc[1][j], 0, 0, 0);
        }
    }

    #pragma unroll
    for (int i = 0; i < 2; ++i)
        #pragma unroll
        for (int j = 0; j < 4; ++j) {
            int c = col0 + j * 16 + l15;
            float bv2 = bias[c];
            #pragma unroll
            for (int r = 0; r < 4; ++r) {
                int m = row0 + w * 32 + i * 16 + l4 * 4 + r;
                Co[(size_t)m * C_ + c] = mish_f(acc[i][j][r] + bv2);
            }
        }
}

// -------------------------------------------------------------------------
extern "C" void kernel_launch(void* const* d_in, const int* in_sizes, int n_in,
                              void* d_out, int out_size, void* d_ws, size_t ws_size,
                              hipStream_t stream) {
    const float* x     = (const float*)d_in[0];
    const float* y     = (const float*)d_in[1];
    const float* t_mat = (const float*)d_in[2];
    const float* wq    = (const float*)d_in[3];
    const float* bq    = (const float*)d_in[4];
    const float* wk    = (const float*)d_in[5];
    const float* bk    = (const float*)d_in[6];
    const float* wv    = (const float*)d_in[7];
    const float* bv    = (const float*)d_in[8];
    const float* wc    = (const float*)d_in[9];
    const float* bc    = (const float*)d_in[10];
    const float* wf    = (const float*)d_in[11];
    const float* bf    = (const float*)d_in[12];
    float* out = (float*)d_out;

    // workspace layout (byte offsets)
    char* base = (char*)d_ws;
    bf16_t* Qt   = (bf16_t*)(base + 0);          //  8 MiB  [b][c][s]
    bf16_t* Kb   = (bf16_t*)(base + 8388608);    //  8 MiB  [b*s][c]
    bf16_t* Vt   = (bf16_t*)(base + 16777216);   //  8 MiB  [b][c][s]
    float*  Mm   = (float*) (base + 25165824);   //  0.5 MiB
    bf16_t* Weft = (bf16_t*)(base + 25690112);   //  4 MiB  [b][co][cin]
    bf16_t* ybf  = (bf16_t*)(base + 29884416);   //  8 MiB
    bf16_t* xbf  = (bf16_t*)(base + 38273024);   //  8 MiB
    bf16_t* wqt  = (bf16_t*)(base + 46661632);   //  2 MiB
    bf16_t* wkt  = (bf16_t*)(base + 48758784);   //  2 MiB
    bf16_t* wvt  = (bf16_t*)(base + 50855936);   //  2 MiB

    hipMemsetAsync(Mm, 0, (size_t)B_ * H_ * 64 * 64 * sizeof(float), stream);

    dim3 blk(256);

    // merged conversions + weight transposes (4864 blocks)
    prep_kernel<<<dim3(4864), blk, 0, stream>>>(
        y, ybf, x, xbf, wq, wk, wv, wqt, wkt, wvt);

    // fused QKV projections (768 blocks)
    qkv_proj<<<dim3(C_ / 128, (B_ * S_) / 128, 3), blk, 0, stream>>>(
        ybf, xbf, wqt, wkt, wvt, bq, bk, bv, Qt, Kb, Vt);

    // fused cv + M-accumulation (2048 blocks)
    cv_qtcv_fused<<<dim3(S_ / 128, 4, B_ * H_), blk, 0, stream>>>(
        t_mat, Vt, Qt, wc, bc, Mm);

    // Weff^T (bf16), 1/8 folded
    weff_kernel<<<dim3(C_ / 64, H_, B_), blk, 0, stream>>>(Mm, wf, Weft);

    // out = mish(K @ Weff + bf), 512 blocks
    final_gemm<<<dim3(C_ / 64, S_ / 128, B_), blk, 0, stream>>>(
        Kb, Weft, bf, out);
}